// Round 9
// baseline (192.173 us; speedup 1.0000x reference)
//
#include <hip/hip_runtime.h>
#include <hip/hip_bf16.h>
#include <stdint.h>

typedef __hip_bfloat16 bf;
typedef __attribute__((ext_vector_type(8))) short short8;
typedef __attribute__((ext_vector_type(4))) short short4v;
typedef __attribute__((ext_vector_type(4))) float float4v;
__device__ __forceinline__ float b2f(bf x){ return __bfloat162float(x); }
__device__ __forceinline__ float bs2f(short s){
    return __uint_as_float(((uint32_t)(uint16_t)s) << 16);
}
__device__ __forceinline__ float sane(float x){ return fminf(fmaxf(x, -1e6f), 1e6f); }
__device__ __forceinline__ float rl(float v, int l){
    return __int_as_float(__builtin_amdgcn_readlane(__float_as_int(v), l));
}

// Problem constants
constexpr int N   = 6144;          // NOT a power of two (3*2^11)!
constexpr int D   = 64;
constexpr int FE  = 32;
constexpr int Eg  = 196608;        // < 2^18 -> edge id packs in 18 bits
constexpr size_t NF = (size_t)N * D;

constexpr float L2E = 1.4426950408889634f;   // log2(e)

__device__ __forceinline__ int clampi(int v){ return v < 0 ? 0 : (v >= N ? N - 1 : v); }
__device__ __forceinline__ float ldf(const void* p, size_t i, uint32_t isf32){
    return isf32 ? ((const float*)p)[i] : b2f(((const bf*)p)[i]);
}

// ---- float workspace layout (floats) ----  ~30.4 MB
constexpr size_t OF_OP   = 0;                           // [4][2][N][D] attn partial O
constexpr size_t OF_LP   = OF_OP + 8*NF;                // [4][2][N]    attn partial L
constexpr size_t OF_CO   = OF_LP + 8*(size_t)N;         // [2][N][D]    corr O (negative)
constexpr size_t OF_CL   = OF_CO + 2*NF;                // [2][N]       corr L (negative)
constexpr size_t OF_MEAN = OF_CL + 2*(size_t)N;         // [2][N][D]
constexpr size_t OF_POOL = OF_MEAN + 2*NF;              // [4][N][FE]
constexpr size_t OF_QKVB = OF_POOL + (size_t)4*N*FE;    // bf16 [2][3][N][D] (Q pre-scaled)
constexpr size_t OF_XF   = OF_QKVB + 3*NF;              // [2][N][D] f32 staged x1,x2
constexpr size_t OF_WA   = OF_XF + 2*NF;                // [6][64][64] attn proj W (f32)
constexpr size_t OF_BA   = OF_WA + 24576;               // [6][64]
constexpr size_t OF_WO   = OF_BA + 384;                 // [2][64][64] Wo_p, Wo_n
constexpr size_t OF_BO   = OF_WO + 8192;                // [2][64]
constexpr size_t OF_WF   = OF_BO + 128;                 // [384][64] final weight
constexpr size_t OF_BF   = OF_WF + 24576;               // [64]
constexpr size_t F_TOTAL = OF_BF + 64;
// ---- u32 workspace (words, after float region) ----  ~3.44 MB
constexpr size_t OI_CNT  = 0;                           // [4][N]
constexpr size_t OI_PTR  = OI_CNT + 4*(size_t)N;        // [4][N+1]
constexpr size_t OI_CUR  = OI_PTR + 4*(size_t)(N+1);    // [4][N]
constexpr size_t OI_PAY  = OI_CUR + 4*(size_t)N;        // [4][Eg]  payload: e | (other<<18)
constexpr size_t OI_FLAG = OI_PAY + 4*(size_t)Eg;       // [4] dtype flags

// zero CSR counts + dtype-sniff fused (last 4 blocks sniff one tensor each).
__global__ void zero_sniff_kernel(uint32_t* __restrict__ uz, int nu,
                                  const void* xA, const void* xB,
                                  const void* xC, const void* xD,
                                  uint32_t* __restrict__ flags){
    int i = blockIdx.x * 256 + threadIdx.x;
    if (i < nu) uz[i] = 0u;
    int sb = (int)gridDim.x - 4;
    if (blockIdx.x >= sb){
        int k = blockIdx.x - sb;
        const void* ps[4] = {xA, xB, xC, xD};
        const bf* p = (const bf*)ps[k];
        __shared__ float red[256];
        int t = threadIdx.x;
        float m = 0.f;
        for (int j = t; j < 1024; j += 256){
            float v = fabsf(b2f(p[j]));
            if (!(v <= 1e9f)) v = 1e9f;
            m = fmaxf(m, v);
        }
        red[t] = m; __syncthreads();
        for (int off = 128; off; off >>= 1){
            if (t < off) red[t] = fmaxf(red[t], red[t + off]);
            __syncthreads();
        }
        if (t == 0) flags[k] = (red[0] > 100.f) ? 1u : 0u;
    }
}

// convert float tensors to f32 staging + CSR count fused (y==3)
__global__ void convert_kernel(const void* x1, const void* x2,
                               const void* W0, const void* W1, const void* W2,
                               const void* W3, const void* W4, const void* W5,
                               const void* B0, const void* B1, const void* B2,
                               const void* B3, const void* B4, const void* B5,
                               const void* Wop, const void* bop,
                               const void* Won, const void* bon,
                               const void* wgt, const void* bia,
                               const int* __restrict__ eip, const int* __restrict__ ein,
                               uint32_t* __restrict__ iws,
                               const uint32_t* __restrict__ flags, float* __restrict__ ws){
    int y = blockIdx.y;
    size_t idx = (size_t)blockIdx.x * 256 + threadIdx.x;
    if (y == 0){
        uint32_t fA = flags[0];
        float v = (idx < NF) ? ldf(x1, idx, fA) : ldf(x2, idx - NF, fA);
        ws[OF_XF + idx] = sane(v);
    } else if (y == 1){
        if (idx >= 33280) return;
        uint32_t fD = flags[3];
        float v;
        if (idx < 24576){
            int m = (int)(idx >> 12), sub = (int)(idx & 4095);
            const void* W = (m==0)?W0:(m==1)?W1:(m==2)?W2:(m==3)?W3:(m==4)?W4:W5;
            v = ldf(W, sub, fD);
        } else if (idx < 24960){
            int m = (int)((idx - 24576) >> 6), sub = (int)(idx & 63);
            const void* B = (m==0)?B0:(m==1)?B1:(m==2)?B2:(m==3)?B3:(m==4)?B4:B5;
            v = ldf(B, sub, fD);
        } else if (idx < 33152){
            int k = (int)((idx - 24960) >> 12), sub = (int)(idx & 4095);
            v = ldf(k ? Won : Wop, sub, fD);
        } else {
            int k = (int)((idx - 33152) >> 6), sub = (int)(idx & 63);
            v = ldf(k ? bon : bop, sub, fD);
        }
        ws[OF_WA + idx] = sane(v);
    } else if (y == 2){
        if (idx >= 24640) return;
        uint32_t fC = flags[2];
        float v = (idx < 24576) ? ldf(wgt, idx, fC) : ldf(bia, idx - 24576, fC);
        ws[OF_WF + idx] = sane(v);
    } else {
        // CSR count (only first 768 x-blocks carry edges)
        if (idx >= (size_t)Eg) return;
        int e = (int)idx;
        uint32_t* cnt = iws + OI_CNT;
        atomicAdd(&cnt[0 * N + clampi(eip[e])],      1u);
        atomicAdd(&cnt[1 * N + clampi(eip[Eg + e])], 1u);
        atomicAdd(&cnt[2 * N + clampi(ein[e])],      1u);
        atomicAdd(&cnt[3 * N + clampi(ein[Eg + e])], 1u);
    }
}

// ---- scan + qkv fused: blocks 0..3 = CSR exclusive scan; rest = qkv ----
__device__ __forceinline__ void scan_role(int b, uint32_t* __restrict__ iws){
    int t = threadIdx.x;
    const uint32_t* c = iws + OI_CNT + (size_t)b * N;
    uint32_t* P  = iws + OI_PTR + (size_t)b * (N + 1);
    uint32_t* Cu = iws + OI_CUR + (size_t)b * N;
    constexpr int K = N / 256;
    int base = t * K;
    uint32_t s = 0;
    for (int k = 0; k < K; ++k) s += c[base + k];
    __shared__ uint32_t sums[256];
    sums[t] = s; __syncthreads();
    for (int off = 1; off < 256; off <<= 1){
        uint32_t v = (t >= off) ? sums[t - off] : 0u;
        __syncthreads();
        sums[t] += v;
        __syncthreads();
    }
    uint32_t run = (t == 0) ? 0u : sums[t - 1];
    for (int k = 0; k < K; ++k){ P[base + k] = run; Cu[base + k] = run; run += c[base + k]; }
    if (t == 255) P[N] = run;
}

__device__ __forceinline__ void qkv_role(int q, const float* __restrict__ ws_ro,
                                         float* __restrict__ ws){
    int m = q / 384, xb = q - m * 384;
    int t = threadIdx.x, lane = t & 63, wv = t >> 6;
    int row0 = xb * 16 + wv * 4;
    const float* x = ws_ro + OF_XF + (m < 3 ? 0 : NF) + (size_t)row0 * 64;
    const float* W = ws_ro + OF_WA + (size_t)m * 4096;
    float x0 = x[lane], x1 = x[64 + lane], x2 = x[128 + lane], x3 = x[192 + lane];
    float bbias = ws_ro[OF_BA + m * 64 + lane];
    float a0 = bbias, a1 = bbias, a2 = bbias, a3 = bbias;
    #pragma unroll 16
    for (int d = 0; d < 64; ++d){
        float w = W[d * 64 + lane];
        a0 += rl(x0, d) * w;
        a1 += rl(x1, d) * w;
        a2 += rl(x2, d) * w;
        a3 += rl(x3, d) * w;
    }
    float sc = (m == 0 || m == 3) ? 0.125f * L2E : 1.f;
    bf* qkvb = (bf*)(ws + OF_QKVB) + (size_t)m * NF + (size_t)row0 * 64;
    qkvb[lane]       = __float2bfloat16(sane(a0) * sc);
    qkvb[64 + lane]  = __float2bfloat16(sane(a1) * sc);
    qkvb[128 + lane] = __float2bfloat16(sane(a2) * sc);
    qkvb[192 + lane] = __float2bfloat16(sane(a3) * sc);
}

__global__ void scan_qkv_kernel(uint32_t* __restrict__ iws,
                                const float* __restrict__ ws_ro, float* __restrict__ ws){
    int b = blockIdx.x;
    if (b < 4) scan_role(b, iws);
    else       qkv_role(b - 4, ws_ro, ws);
}

// ---- mega kernel roles (round 8: 4-edge unrolled gathers for MLP) ----

// mean: 4 groups x 16 lanes; lane covers d = t*4..t*4+3 (float4 gathers)
__device__ __forceinline__ void mean_role(int b, const uint32_t* __restrict__ iws,
                                          const float* __restrict__ ws_ro, float* __restrict__ ws){
    int wid = threadIdx.x >> 6, lane = threadIdx.x & 63;
    int gw = b * 4 + wid;
    int sign = gw >= N;
    int i = gw - sign * N;
    int h = lane >> 4, t = lane & 15;
    const float* x = ws_ro + OF_XF + (size_t)sign * NF;
    int csr = sign ? 2 : 0;
    const uint32_t* P   = iws + OI_PTR + (size_t)csr * (N + 1);
    const uint32_t* Pay = iws + OI_PAY + (size_t)csr * Eg;
    uint32_t p0 = P[i], p1 = P[i + 1];
    if (p1 > (uint32_t)Eg) p1 = Eg;
    if (p0 > p1) p0 = p1;
    float4v acc = (float4v){0.f, 0.f, 0.f, 0.f};
    if (h == 0) acc = *(const float4v*)(x + (size_t)i * 64 + t * 4);   // self loop
    uint32_t p = p0 + h;
    for (; p + 12 < p1; p += 16){
        int cA = (int)(Pay[p]      >> 18);
        int cB = (int)(Pay[p + 4]  >> 18);
        int cC = (int)(Pay[p + 8]  >> 18);
        int cD = (int)(Pay[p + 12] >> 18);
        float4v vA = *(const float4v*)(x + (size_t)cA * 64 + t * 4);
        float4v vB = *(const float4v*)(x + (size_t)cB * 64 + t * 4);
        float4v vC = *(const float4v*)(x + (size_t)cC * 64 + t * 4);
        float4v vD = *(const float4v*)(x + (size_t)cD * 64 + t * 4);
        acc[0] += (vA[0] + vB[0]) + (vC[0] + vD[0]);
        acc[1] += (vA[1] + vB[1]) + (vC[1] + vD[1]);
        acc[2] += (vA[2] + vB[2]) + (vC[2] + vD[2]);
        acc[3] += (vA[3] + vB[3]) + (vC[3] + vD[3]);
    }
    for (; p < p1; p += 4){
        int c = (int)(Pay[p] >> 18);
        float4v v = *(const float4v*)(x + (size_t)c * 64 + t * 4);
        acc[0] += v[0]; acc[1] += v[1]; acc[2] += v[2]; acc[3] += v[3];
    }
    #pragma unroll
    for (int j = 0; j < 4; ++j){
        acc[j] += __shfl_xor(acc[j], 16, 64);
        acc[j] += __shfl_xor(acc[j], 32, 64);
    }
    if (h == 0){
        float invc = 1.f / (float)(p1 - p0 + 1);
        float* dst = ws + OF_MEAN + (size_t)sign * NF + (size_t)i * 64 + t * 4;
        #pragma unroll
        for (int j = 0; j < 4; ++j) dst[j] = sane(acc[j] * invc);
    }
}

// pool: 8 groups x 8 lanes; lane covers f = t*4..t*4+3; 32 edges in flight
__device__ __forceinline__ void pool_role(int b, const void* __restrict__ efp,
                                          const void* __restrict__ efn,
                                          const uint32_t* __restrict__ iws,
                                          uint32_t fB, float* __restrict__ ws){
    int wid = threadIdx.x >> 6, lane = threadIdx.x & 63;
    int gw = b * 4 + wid;
    int g = gw / N, i = gw - g * N;
    const void* ef = (g < 2) ? efp : efn;
    const uint32_t* P   = iws + OI_PTR + (size_t)g * (N + 1);
    const uint32_t* Pay = iws + OI_PAY + (size_t)g * Eg;
    int h = lane >> 3, t = lane & 7;
    uint32_t p0 = P[i], p1 = P[i + 1];
    if (p1 > (uint32_t)Eg) p1 = Eg;
    if (p0 > p1) p0 = p1;
    float m0 = 0.f, m1 = 0.f, m2 = 0.f, m3 = 0.f;
    uint32_t p = p0 + h;
    if (fB){
        const float* E = (const float*)ef;
        for (; p + 24 < p1; p += 32){
            uint32_t eA = Pay[p]      & 0x3FFFFu, eB = Pay[p + 8]  & 0x3FFFFu;
            uint32_t eC = Pay[p + 16] & 0x3FFFFu, eD = Pay[p + 24] & 0x3FFFFu;
            float4v vA = *(const float4v*)(E + (size_t)eA * 32 + t * 4);
            float4v vB = *(const float4v*)(E + (size_t)eB * 32 + t * 4);
            float4v vC = *(const float4v*)(E + (size_t)eC * 32 + t * 4);
            float4v vD = *(const float4v*)(E + (size_t)eD * 32 + t * 4);
            m0 = fmaxf(m0, fmaxf(fmaxf(vA[0], vB[0]), fmaxf(vC[0], vD[0])));
            m1 = fmaxf(m1, fmaxf(fmaxf(vA[1], vB[1]), fmaxf(vC[1], vD[1])));
            m2 = fmaxf(m2, fmaxf(fmaxf(vA[2], vB[2]), fmaxf(vC[2], vD[2])));
            m3 = fmaxf(m3, fmaxf(fmaxf(vA[3], vB[3]), fmaxf(vC[3], vD[3])));
        }
        for (; p < p1; p += 8){
            uint32_t e = Pay[p] & 0x3FFFFu;
            float4v v = *(const float4v*)(E + (size_t)e * 32 + t * 4);
            m0 = fmaxf(m0, v[0]); m1 = fmaxf(m1, v[1]);
            m2 = fmaxf(m2, v[2]); m3 = fmaxf(m3, v[3]);
        }
    } else {
        const short* E = (const short*)ef;
        for (; p + 24 < p1; p += 32){
            uint32_t eA = Pay[p]      & 0x3FFFFu, eB = Pay[p + 8]  & 0x3FFFFu;
            uint32_t eC = Pay[p + 16] & 0x3FFFFu, eD = Pay[p + 24] & 0x3FFFFu;
            short4v vA = *(const short4v*)(E + (size_t)eA * 32 + t * 4);
            short4v vB = *(const short4v*)(E + (size_t)eB * 32 + t * 4);
            short4v vC = *(const short4v*)(E + (size_t)eC * 32 + t * 4);
            short4v vD = *(const short4v*)(E + (size_t)eD * 32 + t * 4);
            m0 = fmaxf(m0, fmaxf(fmaxf(bs2f(vA[0]), bs2f(vB[0])), fmaxf(bs2f(vC[0]), bs2f(vD[0]))));
            m1 = fmaxf(m1, fmaxf(fmaxf(bs2f(vA[1]), bs2f(vB[1])), fmaxf(bs2f(vC[1]), bs2f(vD[1]))));
            m2 = fmaxf(m2, fmaxf(fmaxf(bs2f(vA[2]), bs2f(vB[2])), fmaxf(bs2f(vC[2]), bs2f(vD[2]))));
            m3 = fmaxf(m3, fmaxf(fmaxf(bs2f(vA[3]), bs2f(vB[3])), fmaxf(bs2f(vC[3]), bs2f(vD[3]))));
        }
        for (; p < p1; p += 8){
            uint32_t e = Pay[p] & 0x3FFFFu;
            short4v v = *(const short4v*)(E + (size_t)e * 32 + t * 4);
            m0 = fmaxf(m0, bs2f(v[0])); m1 = fmaxf(m1, bs2f(v[1]));
            m2 = fmaxf(m2, bs2f(v[2])); m3 = fmaxf(m3, bs2f(v[3]));
        }
    }
    #pragma unroll
    for (int mk = 8; mk <= 32; mk <<= 1){
        m0 = fmaxf(m0, __shfl_xor(m0, mk, 64));
        m1 = fmaxf(m1, __shfl_xor(m1, mk, 64));
        m2 = fmaxf(m2, __shfl_xor(m2, mk, 64));
        m3 = fmaxf(m3, __shfl_xor(m3, mk, 64));
    }
    m0 = sane(m0); m1 = sane(m1); m2 = sane(m2); m3 = sane(m3);
    float ss = m0 * m0 + m1 * m1 + m2 * m2 + m3 * m3;
    ss += __shfl_xor(ss, 1, 64); ss += __shfl_xor(ss, 2, 64); ss += __shfl_xor(ss, 4, 64);
    float inv = 1.f / fmaxf(sqrtf(ss), 1e-12f);
    if (h == 0){
        float* dst = ws + OF_POOL + ((size_t)g * N + i) * 32 + t * 4;
        dst[0] = sane(m0 * inv); dst[1] = sane(m1 * inv);
        dst[2] = sane(m2 * inv); dst[3] = sane(m3 * inv);
    }
}

// corr: 8 groups x 8 lanes; 4-edge unroll (8 x 16B loads in flight);
// diagonal = slot p1. Plain stores into CO/CL (negated), no atomics.
__device__ __forceinline__ void corr_role(int b, const uint32_t* __restrict__ iws,
                                          const float* __restrict__ ws_ro,
                                          float* __restrict__ CO, float* __restrict__ CL){
    int wid = threadIdx.x >> 6, lane = threadIdx.x & 63;
    int gw = b * 4 + wid;
    int sg = gw >= N;
    int i = gw - sg * N;
    int h = lane >> 3, t = lane & 7;
    const bf* Qb = (const bf*)(ws_ro + OF_QKVB) + (size_t)(sg * 3) * NF;
    const short* Kb = (const short*)(Qb + NF);
    const short* Vb = Kb + NF;
    const int csr = sg ? 2 : 0;
    const uint32_t* Pp  = iws + OI_PTR + (size_t)csr * (N + 1);
    const uint32_t* Pay = iws + OI_PAY + (size_t)csr * Eg;
    uint32_t p0 = Pp[i], p1 = Pp[i + 1];
    if (p1 > (uint32_t)Eg) p1 = Eg;
    if (p0 > p1) p0 = p1;
    float qf[8];
    {
        short8 qv = *(const short8*)((const short*)Qb + (size_t)i * 64 + t * 8);
        #pragma unroll
        for (int j = 0; j < 8; ++j) qf[j] = bs2f(qv[j]);   // pre-scaled 0.125*log2e
    }
    float accO[8] = {0.f,0.f,0.f,0.f,0.f,0.f,0.f,0.f};
    float accL = 0.f;
    constexpr float C = 0.63212055882f;      // 1 - 1/e
    uint32_t p = p0 + h;
    // main: 4 slots {p, p+8, p+16, p+24}; only the last can be the diagonal
    for (; p + 24 <= p1; p += 32){
        int cA = (int)(Pay[p]      >> 18);
        int cB = (int)(Pay[p + 8]  >> 18);
        int cC = (int)(Pay[p + 16] >> 18);
        int cD = (p + 24 < p1) ? (int)(Pay[p + 24] >> 18) : i;
        short8 kvA = *(const short8*)(Kb + (size_t)cA * 64 + t * 8);
        short8 kvB = *(const short8*)(Kb + (size_t)cB * 64 + t * 8);
        short8 kvC = *(const short8*)(Kb + (size_t)cC * 64 + t * 8);
        short8 kvD = *(const short8*)(Kb + (size_t)cD * 64 + t * 8);
        short8 vvA = *(const short8*)(Vb + (size_t)cA * 64 + t * 8);
        short8 vvB = *(const short8*)(Vb + (size_t)cB * 64 + t * 8);
        short8 vvC = *(const short8*)(Vb + (size_t)cC * 64 + t * 8);
        short8 vvD = *(const short8*)(Vb + (size_t)cD * 64 + t * 8);
        float sA = qf[0] * bs2f(kvA[0]);
        float sB = qf[0] * bs2f(kvB[0]);
        float sC = qf[0] * bs2f(kvC[0]);
        float sD = qf[0] * bs2f(kvD[0]);
        #pragma unroll
        for (int j = 1; j < 8; ++j){
            sA += qf[j] * bs2f(kvA[j]); sB += qf[j] * bs2f(kvB[j]);
            sC += qf[j] * bs2f(kvC[j]); sD += qf[j] * bs2f(kvD[j]);
        }
        sA += __shfl_xor(sA, 1, 64); sB += __shfl_xor(sB, 1, 64);
        sC += __shfl_xor(sC, 1, 64); sD += __shfl_xor(sD, 1, 64);
        sA += __shfl_xor(sA, 2, 64); sB += __shfl_xor(sB, 2, 64);
        sC += __shfl_xor(sC, 2, 64); sD += __shfl_xor(sD, 2, 64);
        sA += __shfl_xor(sA, 4, 64); sB += __shfl_xor(sB, 4, 64);
        sC += __shfl_xor(sC, 4, 64); sD += __shfl_xor(sD, 4, 64);
        float fA = C * __builtin_amdgcn_exp2f(sA + L2E);
        float fB = C * __builtin_amdgcn_exp2f(sB + L2E);
        float fC = C * __builtin_amdgcn_exp2f(sC + L2E);
        float fD = C * __builtin_amdgcn_exp2f(sD + L2E);
        accL += (fA + fB) + (fC + fD);
        #pragma unroll
        for (int j = 0; j < 8; ++j)
            accO[j] += (fA * bs2f(vvA[j]) + fB * bs2f(vvB[j]))
                     + (fC * bs2f(vvC[j]) + fD * bs2f(vvD[j]));
    }
    for (; p <= p1; p += 8){
        int c = (p < p1) ? (int)(Pay[p] >> 18) : i;
        short8 kv = *(const short8*)(Kb + (size_t)c * 64 + t * 8);
        short8 vv = *(const short8*)(Vb + (size_t)c * 64 + t * 8);
        float s = qf[0] * bs2f(kv[0]);
        #pragma unroll
        for (int j = 1; j < 8; ++j) s += qf[j] * bs2f(kv[j]);
        s += __shfl_xor(s, 1, 64);
        s += __shfl_xor(s, 2, 64);
        s += __shfl_xor(s, 4, 64);
        float f = C * __builtin_amdgcn_exp2f(s + L2E);
        accL += f;
        #pragma unroll
        for (int j = 0; j < 8; ++j) accO[j] += f * bs2f(vv[j]);
    }
    #pragma unroll
    for (int j = 0; j < 8; ++j){
        accO[j] += __shfl_xor(accO[j], 8, 64);
        accO[j] += __shfl_xor(accO[j], 16, 64);
        accO[j] += __shfl_xor(accO[j], 32, 64);
    }
    accL += __shfl_xor(accL, 8, 64);
    accL += __shfl_xor(accL, 16, 64);
    accL += __shfl_xor(accL, 32, 64);
    if (h == 0){
        float* Op = CO + ((size_t)sg * N + i) * 64 + t * 8;
        #pragma unroll
        for (int j = 0; j < 8; ++j) Op[j] = -accO[j];
        if (t == 0) CL[(size_t)sg * N + i] = -accL;
    }
}

__global__ void mega_kernel(const void* __restrict__ efp, const void* __restrict__ efn,
                            const uint32_t* __restrict__ iws,
                            const uint32_t* __restrict__ flags, float* __restrict__ ws){
    int b = blockIdx.x;
    if (b < 3072)       mean_role(b, iws, ws, ws);
    else if (b < 9216)  pool_role(b - 3072, efp, efn, iws, flags[1], ws);
    else                corr_role(b - 9216, iws, ws, ws + OF_CO, ws + OF_CL);
}

// ---- dense attention role + CSR fill role fused ----
#define GLB1(p) ((const __attribute__((address_space(1))) void*)(p))
#define LDS3(p) ((__attribute__((address_space(3))) void*)(p))

__device__ __forceinline__ uint32_t lds_off32(const void* p){
    return (uint32_t)(uintptr_t)(__attribute__((address_space(3))) const void*)p;
}
__device__ __forceinline__ short8 ds_read_b128_off(uint32_t addr, int off){
    short8 r;
    asm volatile("ds_read_b128 %0, %1 offset:%2" : "=v"(r) : "v"(addr), "i"(off));
    return r;
}
__device__ __forceinline__ unsigned long long ds_tr16(uint32_t addr, int off){
    unsigned long long r;
    asm volatile("ds_read_b64_tr_b16 %0, %1 offset:%2" : "=v"(r) : "v"(addr), "i"(off));
    return r;
}
__device__ __forceinline__ unsigned cvt_pk_bf16(float lo, float hi){
    unsigned r;
    asm("v_cvt_pk_bf16_f32 %0, %1, %2" : "=v"(r) : "v"(lo), "v"(hi));
    return r;
}

__device__ void attn_role(int ab, short* lds_s, const bf* __restrict__ qkvb,
                          float* __restrict__ OP, float* __restrict__ LP){
    int tid = threadIdx.x, lane = tid & 63, wv = tid >> 6;
    int m16 = lane & 15, quad = lane >> 4;
    int rt = ab % 96, cs = (ab / 96) & 3, sg = ab / 384;
    const bf* Qb = qkvb + (size_t)(sg * 3) * NF;
    const bf* Kb = Qb + NF;
    const bf* Vb = Kb + NF;

    int rowbase = rt * 64 + wv * 16;
    short8 Qf0 = *(const short8*)(Qb + (size_t)(rowbase + m16) * 64 + quad * 8);
    short8 Qf1 = *(const short8*)(Qb + (size_t)(rowbase + m16) * 64 + 32 + quad * 8);

    float4v Oc[4];
    #pragma unroll
    for (int t = 0; t < 4; ++t) Oc[t] = (float4v){0.f, 0.f, 0.f, 0.f};
    float l = 0.f;

    const uint32_t lds0 = lds_off32(lds_s);

    auto stage = [&](int cb, int b){
        char* kdst = (char*)lds_s + b * 8192 + wv * 2048;
        char* vdst = (char*)lds_s + 16384 + b * 8192 + wv * 2048;
        #pragma unroll
        for (int inst = 0; inst < 2; ++inst){
            int Lb = wv * 2048 + inst * 1024 + lane * 16;   // dest byte in 8KB buf
            int cl = Lb >> 7;
            int gc = (cl & 32) | (((cl >> 2) & 3) << 3) | (((cl >> 4) & 1) << 2) | (cl & 3);
            int d2 = (Lb & 127) ^ ((cl & 7) << 4);
            const char* ksrc = (const char*)Kb + (((size_t)(cb + gc)) << 7) + d2;
            __builtin_amdgcn_global_load_lds(GLB1(ksrc), LDS3(kdst + inst * 1024), 16, 0, 0);
            int idx = Lb >> 1;
            int vc  = ((idx >> 8) << 2) | ((idx >> 4) & 3);
            int vd  = (((idx >> 6) & 3) << 4) | (idx & 8);
            const char* vsrc = (const char*)Vb + (((size_t)(cb + vc)) << 7) + (vd << 1);
            __builtin_amdgcn_global_load_lds(GLB1(vsrc), LDS3(vdst + inst * 1024), 16, 0, 0);
        }
    };

    const int sw16 = (m16 & 7) << 4;                 // K read swizzle (lane-const)
    const uint32_t kx0 = (uint32_t)(m16 * 128 + ((quad * 16) ^ sw16));
    const uint32_t kx1 = (uint32_t)(m16 * 128 + (((64 + quad * 16)) ^ sw16));
    const uint32_t vx  = (uint32_t)(quad * 1024 + m16 * 2);

    int c0 = cs * (N / 4), c1 = c0 + N / 4;
    stage(c0, 0);
    asm volatile("s_waitcnt vmcnt(0)" ::: "memory");
    __syncthreads();

    int buf = 0;
    for (int cb = c0; cb < c1; cb += 64){
        if (cb + 64 < c1) stage(cb + 64, buf ^ 1);   // prefetch next tile (other buf)
        uint32_t kb0 = lds0 + (uint32_t)(buf * 8192) + kx0;
        uint32_t kb1 = lds0 + (uint32_t)(buf * 8192) + kx1;
        uint32_t vab = lds0 + 16384u + (uint32_t)(buf * 8192) + vx;
        #pragma unroll
        for (int kg = 0; kg < 2; ++kg){
            short8 A[2][2];
            #pragma unroll
            for (int ct = 0; ct < 2; ++ct){
                A[ct][0] = ds_read_b128_off(kb0, kg * 4096 + ct * 2048);
                A[ct][1] = ds_read_b128_off(kb1, kg * 4096 + ct * 2048);
            }
            unsigned long long tr[8];
            #pragma unroll
            for (int dt = 0; dt < 4; ++dt)
                #pragma unroll
                for (int w = 0; w < 2; ++w)
                    tr[dt * 2 + w] = ds_tr16(vab, kg * 4096 + w * 512 + dt * 128);
            asm volatile("s_waitcnt lgkmcnt(8)" ::: "memory");  // K frags done
            __builtin_amdgcn_sched_barrier(0);
            float4v s0 = __builtin_amdgcn_mfma_f32_16x16x32_bf16(
                             A[0][0], Qf0, (float4v){0.f,0.f,0.f,0.f}, 0, 0, 0);
            s0 = __builtin_amdgcn_mfma_f32_16x16x32_bf16(A[0][1], Qf1, s0, 0, 0, 0);
            float4v s1 = __builtin_amdgcn_mfma_f32_16x16x32_bf16(
                             A[1][0], Qf0, (float4v){0.f,0.f,0.f,0.f}, 0, 0, 0);
            s1 = __builtin_amdgcn_mfma_f32_16x16x32_bf16(A[1][1], Qf1, s1, 0, 0, 0);
            float p0[4], p1[4];
            #pragma unroll
            for (int r = 0; r < 4; ++r){
                p0[r] = __builtin_amdgcn_exp2f(s0[r] + L2E);
                p1[r] = __builtin_amdgcn_exp2f(s1[r] + L2E);
                l += p0[r] + p1[r];
            }
            union { unsigned u[4]; short8 s8; } pf;
            pf.u[0] = cvt_pk_bf16(p0[0], p0[1]);
            pf.u[1] = cvt_pk_bf16(p0[2], p0[3]);
            pf.u[2] = cvt_pk_bf16(p1[0], p1[1]);
            pf.u[3] = cvt_pk_bf16(p1[2], p1[3]);
            asm volatile("s_waitcnt lgkmcnt(0)" ::: "memory");  // tr reads done
            __builtin_amdgcn_sched_barrier(0);
            #pragma unroll
            for (int dt = 0; dt < 4; ++dt){
                union { unsigned long long u[2]; short8 s8; } va;
                va.u[0] = tr[dt * 2];
                va.u[1] = tr[dt * 2 + 1];
                Oc[dt] = __builtin_amdgcn_mfma_f32_16x16x32_bf16(va.s8, pf.s8, Oc[dt], 0, 0, 0);
            }
        }
        asm volatile("s_waitcnt vmcnt(0)" ::: "memory");  // prefetch landed
        __syncthreads();                                   // all waves done with buf
        buf ^= 1;
    }

    l += __shfl_xor(l, 16, 64);
    l += __shfl_xor(l, 32, 64);
    int slab = cs * 2 + sg;
    if (quad == 0) LP[(size_t)slab * N + rowbase + m16] = l;
    float* Op = OP + ((size_t)slab * N + rowbase + m16) * 64;
    #pragma unroll
    for (int dt = 0; dt < 4; ++dt)
        *(float4v*)(Op + dt * 16 + quad * 4) = Oc[dt];
}

// Round 8: launch_bounds (256,5) — 5 blocks/CU (LDS limit), was 3. More
// resident waves hide the per-tile vmcnt(0)+barrier drain.
__global__ void __launch_bounds__(256, 5)
attn_fill_kernel(const int* __restrict__ eip, const int* __restrict__ ein,
                 uint32_t* __restrict__ iws, const bf* __restrict__ qkvb,
                 float* __restrict__ OP, float* __restrict__ LP){
    __shared__ __align__(16) short lds_s[16384];   // 32 KiB (attn role only)
    int b = blockIdx.x;
    if (b < 768){
        attn_role(b, lds_s, qkvb, OP, LP);
        return;
    }
    int e = (b - 768) * 256 + threadIdx.x;
    if (e >= Eg) return;
    uint32_t* Cu  = iws + OI_CUR;
    uint32_t* Pay = iws + OI_PAY;
    int rp = clampi(eip[e]), cp = clampi(eip[Eg + e]);
    int rn = clampi(ein[e]), cn = clampi(ein[Eg + e]);
    uint32_t p;
    p = atomicAdd(&Cu[0 * N + rp], 1u); if (p < Eg) Pay[0 * (size_t)Eg + p] = (uint32_t)e | ((uint32_t)cp << 18);
    p = atomicAdd(&Cu[1 * N + cp], 1u); if (p < Eg) Pay[1 * (size_t)Eg + p] = (uint32_t)e | ((uint32_t)rp << 18);
    p = atomicAdd(&Cu[2 * N + rn], 1u); if (p < Eg) Pay[2 * (size_t)Eg + p] = (uint32_t)e | ((uint32_t)cn << 18);
    p = atomicAdd(&Cu[3 * N + cn], 1u); if (p < Eg) Pay[3 * (size_t)Eg + p] = (uint32_t)e | ((uint32_t)rn << 18);
}

// final: 4 rows/wave in registers, readlane broadcast, W streamed once/wave.
// O/l assembled from 4 attn partials + corr buffer (no atomics upstream).
__global__ void final_kernel(const uint32_t* __restrict__ flags,
                             const float* __restrict__ ws, void* __restrict__ outv){
    uint32_t fA = flags[0];
    int t = threadIdx.x, lane = t & 63, wv = t >> 6;
    int row0 = blockIdx.x * 16 + wv * 4;
    float fr[6][4];
    #pragma unroll
    for (int s = 0; s < 2; ++s){
        float onr[4];
        #pragma unroll
        for (int r = 0; r < 4; ++r){
            int i = row0 + r;
            float osum = ws[OF_CO + ((size_t)s * N + i) * 64 + lane];
            float lsum = ws[OF_CL + (size_t)s * N + i];
            #pragma unroll
            for (int cs = 0; cs < 4; ++cs){
                int slab = cs * 2 + s;
                osum += ws[OF_OP + ((size_t)slab * N + i) * 64 + lane];
                lsum += ws[OF_LP + (size_t)slab * N + i];
            }
            onr[r] = sane(osum / fmaxf(lsum, 1e-20f));
        }
        const float* Wo = ws + OF_WO + (size_t)s * 4096;
        float b0 = ws[OF_BO + s * 64 + lane];
        float a[4] = {b0, b0, b0, b0};
        #pragma unroll 16
        for (int d = 0; d < 64; ++d){
            float w = Wo[d * 64 + lane];
            a[0] += rl(onr[0], d) * w;
            a[1] += rl(onr[1], d) * w;
            a[2] += rl(onr[2], d) * w;
            a[3] += rl(onr[3], d) * w;
        }
        #pragma unroll
        for (int r = 0; r < 4; ++r){
            int i = row0 + r;
            float mean = ws[OF_MEAN + (size_t)s * NF + (size_t)i * 64 + lane];
            fr[s][r] = sane(mean + a[r]);
        }
    }
    {
        int g0 = lane >> 5, f = lane & 31;
        #pragma unroll
        for (int r = 0; r < 4; ++r){
            int i = row0 + r;
            fr[2][r] = ws[OF_XF + (size_t)i * 64 + lane];
            fr[3][r] = ws[OF_XF + NF + (size_t)i * 64 + lane];
            fr[4][r] = ws[OF_POOL + ((size_t)g0 * N + i) * 32 + f];
            fr[5][r] = ws[OF_POOL + ((size_t)(2 + g0) * N + i) * 32 + f];
        }
    }
    const float* WF = ws + OF_WF;
    float bf0 = ws[OF_BF + lane];
    float acc[4] = {bf0, bf0, bf0, bf0};
    #pragma unroll
    for (int j = 0; j < 6; ++j){
        #pragma unroll 16
        for (int dd = 0; dd < 64; ++dd){
            float w = WF[(size_t)(j * 64 + dd) * 64 + lane];
            acc[0] += rl(fr[j][0], dd) * w;
            acc[1] += rl(fr[j][1], dd) * w;
            acc[2] += rl(fr[j][2], dd) * w;
            acc[3] += rl(fr[j][3], dd) * w;
        }
    }
    #pragma unroll
    for (int r = 0; r < 4; ++r){
        float a = sane(acc[r]);
        float ss = a * a;
        ss += __shfl_xor(ss, 32, 64); ss += __shfl_xor(ss, 16, 64); ss += __shfl_xor(ss, 8, 64);
        ss += __shfl_xor(ss, 4, 64);  ss += __shfl_xor(ss, 2, 64);  ss += __shfl_xor(ss, 1, 64);
        float out = a / fmaxf(sqrtf(ss), 1e-12f);
        int i = row0 + r;
        if (fA) ((float*)outv)[(size_t)i * 64 + lane] = out;
        else    ((bf*)outv)[(size_t)i * 64 + lane] = __float2bfloat16(out);
    }
}

extern "C" void kernel_launch(void* const* d_in, const int* in_sizes, int n_in,
                              void* d_out, int out_size, void* d_ws, size_t ws_size,
                              hipStream_t stream){
    const int* eip = (const int*)d_in[2];
    const int* ein = (const int*)d_in[3];

    float* ws = (float*)d_ws;
    uint32_t* iws = (uint32_t*)(ws + F_TOTAL);
    uint32_t* flags = iws + OI_FLAG;
    bf* qkvb = (bf*)(ws + OF_QKVB);

    int nu = 4 * N;                        // CSR counts
    zero_sniff_kernel<<<dim3((nu + 255) / 256), 256, 0, stream>>>(
        iws + OI_CNT, nu, d_in[0], d_in[4], d_in[6], d_in[8], flags);
    convert_kernel<<<dim3(3072, 4), 256, 0, stream>>>(
        d_in[0], d_in[1],
        d_in[8],  d_in[10], d_in[12], d_in[16], d_in[18], d_in[20],
        d_in[9],  d_in[11], d_in[13], d_in[17], d_in[19], d_in[21],
        d_in[14], d_in[15], d_in[22], d_in[23],
        d_in[6],  d_in[7],
        eip, ein, iws,
        flags, ws);
    scan_qkv_kernel<<<dim3(4 + 2304), 256, 0, stream>>>(iws, ws, ws);
    attn_fill_kernel<<<dim3(768 + 768), 256, 0, stream>>>(
        eip, ein, iws, qkvb, ws + OF_OP, ws + OF_LP);
    mega_kernel<<<dim3(12288), 256, 0, stream>>>(d_in[4], d_in[5], iws, flags, ws);
    final_kernel<<<dim3(N / 16), 256, 0, stream>>>(flags, ws, d_out);
}

// Round 10
// 190.745 us; speedup vs baseline: 1.0075x; 1.0075x over previous
//
#include <hip/hip_runtime.h>
#include <hip/hip_bf16.h>
#include <stdint.h>

typedef __hip_bfloat16 bf;
typedef __attribute__((ext_vector_type(8))) short short8;
typedef __attribute__((ext_vector_type(4))) short short4v;
typedef __attribute__((ext_vector_type(4))) float float4v;
__device__ __forceinline__ float b2f(bf x){ return __bfloat162float(x); }
__device__ __forceinline__ float bs2f(short s){
    return __uint_as_float(((uint32_t)(uint16_t)s) << 16);
}
__device__ __forceinline__ float sane(float x){ return fminf(fmaxf(x, -1e6f), 1e6f); }
__device__ __forceinline__ float rl(float v, int l){
    return __int_as_float(__builtin_amdgcn_readlane(__float_as_int(v), l));
}

// Problem constants
constexpr int N   = 6144;          // NOT a power of two (3*2^11)!
constexpr int D   = 64;
constexpr int FE  = 32;
constexpr int Eg  = 196608;        // < 2^18 -> edge id packs in 18 bits
constexpr size_t NF = (size_t)N * D;

constexpr float L2E = 1.4426950408889634f;   // log2(e)

__device__ __forceinline__ int clampi(int v){ return v < 0 ? 0 : (v >= N ? N - 1 : v); }
__device__ __forceinline__ float ldf(const void* p, size_t i, uint32_t isf32){
    return isf32 ? ((const float*)p)[i] : b2f(((const bf*)p)[i]);
}

// ---- float workspace layout (floats) ----  ~30.4 MB
constexpr size_t OF_OP   = 0;                           // [4][2][N][D] attn partial O
constexpr size_t OF_LP   = OF_OP + 8*NF;                // [4][2][N]    attn partial L
constexpr size_t OF_CO   = OF_LP + 8*(size_t)N;         // [2][N][D]    corr O (negative)
constexpr size_t OF_CL   = OF_CO + 2*NF;                // [2][N]       corr L (negative)
constexpr size_t OF_MEAN = OF_CL + 2*(size_t)N;         // [2][N][D]
constexpr size_t OF_POOL = OF_MEAN + 2*NF;              // [4][N][FE]
constexpr size_t OF_QKVB = OF_POOL + (size_t)4*N*FE;    // bf16 [2][3][N][D] (Q pre-scaled)
constexpr size_t OF_XF   = OF_QKVB + 3*NF;              // [2][N][D] f32 staged x1,x2
constexpr size_t OF_WA   = OF_XF + 2*NF;                // [6][64][64] attn proj W (f32)
constexpr size_t OF_BA   = OF_WA + 24576;               // [6][64]
constexpr size_t OF_WO   = OF_BA + 384;                 // [2][64][64] Wo_p, Wo_n
constexpr size_t OF_BO   = OF_WO + 8192;                // [2][64]
constexpr size_t OF_WF   = OF_BO + 128;                 // [384][64] final weight
constexpr size_t OF_BF   = OF_WF + 24576;               // [64]
constexpr size_t F_TOTAL = OF_BF + 64;
// ---- u32 workspace (words, after float region) ----  ~3.44 MB
constexpr size_t OI_CNT  = 0;                           // [4][N]
constexpr size_t OI_PTR  = OI_CNT + 4*(size_t)N;        // [4][N+1]
constexpr size_t OI_CUR  = OI_PTR + 4*(size_t)(N+1);    // [4][N]
constexpr size_t OI_PAY  = OI_CUR + 4*(size_t)N;        // [4][Eg]  payload: e | (other<<18)
constexpr size_t OI_FLAG = OI_PAY + 4*(size_t)Eg;       // [4] dtype flags

// zero CSR counts + dtype-sniff fused (last 4 blocks sniff one tensor each).
__global__ void zero_sniff_kernel(uint32_t* __restrict__ uz, int nu,
                                  const void* xA, const void* xB,
                                  const void* xC, const void* xD,
                                  uint32_t* __restrict__ flags){
    int i = blockIdx.x * 256 + threadIdx.x;
    if (i < nu) uz[i] = 0u;
    int sb = (int)gridDim.x - 4;
    if (blockIdx.x >= sb){
        int k = blockIdx.x - sb;
        const void* ps[4] = {xA, xB, xC, xD};
        const bf* p = (const bf*)ps[k];
        __shared__ float red[256];
        int t = threadIdx.x;
        float m = 0.f;
        for (int j = t; j < 1024; j += 256){
            float v = fabsf(b2f(p[j]));
            if (!(v <= 1e9f)) v = 1e9f;
            m = fmaxf(m, v);
        }
        red[t] = m; __syncthreads();
        for (int off = 128; off; off >>= 1){
            if (t < off) red[t] = fmaxf(red[t], red[t + off]);
            __syncthreads();
        }
        if (t == 0) flags[k] = (red[0] > 100.f) ? 1u : 0u;
    }
}

// convert float tensors to f32 staging + CSR count fused (y==3)
__global__ void convert_kernel(const void* x1, const void* x2,
                               const void* W0, const void* W1, const void* W2,
                               const void* W3, const void* W4, const void* W5,
                               const void* B0, const void* B1, const void* B2,
                               const void* B3, const void* B4, const void* B5,
                               const void* Wop, const void* bop,
                               const void* Won, const void* bon,
                               const void* wgt, const void* bia,
                               const int* __restrict__ eip, const int* __restrict__ ein,
                               uint32_t* __restrict__ iws,
                               const uint32_t* __restrict__ flags, float* __restrict__ ws){
    int y = blockIdx.y;
    size_t idx = (size_t)blockIdx.x * 256 + threadIdx.x;
    if (y == 0){
        uint32_t fA = flags[0];
        float v = (idx < NF) ? ldf(x1, idx, fA) : ldf(x2, idx - NF, fA);
        ws[OF_XF + idx] = sane(v);
    } else if (y == 1){
        if (idx >= 33280) return;
        uint32_t fD = flags[3];
        float v;
        if (idx < 24576){
            int m = (int)(idx >> 12), sub = (int)(idx & 4095);
            const void* W = (m==0)?W0:(m==1)?W1:(m==2)?W2:(m==3)?W3:(m==4)?W4:W5;
            v = ldf(W, sub, fD);
        } else if (idx < 24960){
            int m = (int)((idx - 24576) >> 6), sub = (int)(idx & 63);
            const void* B = (m==0)?B0:(m==1)?B1:(m==2)?B2:(m==3)?B3:(m==4)?B4:B5;
            v = ldf(B, sub, fD);
        } else if (idx < 33152){
            int k = (int)((idx - 24960) >> 12), sub = (int)(idx & 4095);
            v = ldf(k ? Won : Wop, sub, fD);
        } else {
            int k = (int)((idx - 33152) >> 6), sub = (int)(idx & 63);
            v = ldf(k ? bon : bop, sub, fD);
        }
        ws[OF_WA + idx] = sane(v);
    } else if (y == 2){
        if (idx >= 24640) return;
        uint32_t fC = flags[2];
        float v = (idx < 24576) ? ldf(wgt, idx, fC) : ldf(bia, idx - 24576, fC);
        ws[OF_WF + idx] = sane(v);
    } else {
        // CSR count (only first 768 x-blocks carry edges)
        if (idx >= (size_t)Eg) return;
        int e = (int)idx;
        uint32_t* cnt = iws + OI_CNT;
        atomicAdd(&cnt[0 * N + clampi(eip[e])],      1u);
        atomicAdd(&cnt[1 * N + clampi(eip[Eg + e])], 1u);
        atomicAdd(&cnt[2 * N + clampi(ein[e])],      1u);
        atomicAdd(&cnt[3 * N + clampi(ein[Eg + e])], 1u);
    }
}

// ---- scan + qkv fused: blocks 0..3 = CSR exclusive scan; rest = qkv ----
__device__ __forceinline__ void scan_role(int b, uint32_t* __restrict__ iws){
    int t = threadIdx.x;
    const uint32_t* c = iws + OI_CNT + (size_t)b * N;
    uint32_t* P  = iws + OI_PTR + (size_t)b * (N + 1);
    uint32_t* Cu = iws + OI_CUR + (size_t)b * N;
    constexpr int K = N / 256;
    int base = t * K;
    uint32_t s = 0;
    for (int k = 0; k < K; ++k) s += c[base + k];
    __shared__ uint32_t sums[256];
    sums[t] = s; __syncthreads();
    for (int off = 1; off < 256; off <<= 1){
        uint32_t v = (t >= off) ? sums[t - off] : 0u;
        __syncthreads();
        sums[t] += v;
        __syncthreads();
    }
    uint32_t run = (t == 0) ? 0u : sums[t - 1];
    for (int k = 0; k < K; ++k){ P[base + k] = run; Cu[base + k] = run; run += c[base + k]; }
    if (t == 255) P[N] = run;
}

__device__ __forceinline__ void qkv_role(int q, const float* __restrict__ ws_ro,
                                         float* __restrict__ ws){
    int m = q / 384, xb = q - m * 384;
    int t = threadIdx.x, lane = t & 63, wv = t >> 6;
    int row0 = xb * 16 + wv * 4;
    const float* x = ws_ro + OF_XF + (m < 3 ? 0 : NF) + (size_t)row0 * 64;
    const float* W = ws_ro + OF_WA + (size_t)m * 4096;
    float x0 = x[lane], x1 = x[64 + lane], x2 = x[128 + lane], x3 = x[192 + lane];
    float bbias = ws_ro[OF_BA + m * 64 + lane];
    float a0 = bbias, a1 = bbias, a2 = bbias, a3 = bbias;
    #pragma unroll 16
    for (int d = 0; d < 64; ++d){
        float w = W[d * 64 + lane];
        a0 += rl(x0, d) * w;
        a1 += rl(x1, d) * w;
        a2 += rl(x2, d) * w;
        a3 += rl(x3, d) * w;
    }
    float sc = (m == 0 || m == 3) ? 0.125f * L2E : 1.f;
    bf* qkvb = (bf*)(ws + OF_QKVB) + (size_t)m * NF + (size_t)row0 * 64;
    qkvb[lane]       = __float2bfloat16(sane(a0) * sc);
    qkvb[64 + lane]  = __float2bfloat16(sane(a1) * sc);
    qkvb[128 + lane] = __float2bfloat16(sane(a2) * sc);
    qkvb[192 + lane] = __float2bfloat16(sane(a3) * sc);
}

__global__ void scan_qkv_kernel(uint32_t* __restrict__ iws,
                                const float* __restrict__ ws_ro, float* __restrict__ ws){
    int b = blockIdx.x;
    if (b < 4) scan_role(b, iws);
    else       qkv_role(b - 4, ws_ro, ws);
}

// ---- mega kernel roles (4-edge unrolled gathers for MLP) ----

// mean: 4 groups x 16 lanes; lane covers d = t*4..t*4+3 (float4 gathers)
__device__ __forceinline__ void mean_role(int b, const uint32_t* __restrict__ iws,
                                          const float* __restrict__ ws_ro, float* __restrict__ ws){
    int wid = threadIdx.x >> 6, lane = threadIdx.x & 63;
    int gw = b * 4 + wid;
    int sign = gw >= N;
    int i = gw - sign * N;
    int h = lane >> 4, t = lane & 15;
    const float* x = ws_ro + OF_XF + (size_t)sign * NF;
    int csr = sign ? 2 : 0;
    const uint32_t* P   = iws + OI_PTR + (size_t)csr * (N + 1);
    const uint32_t* Pay = iws + OI_PAY + (size_t)csr * Eg;
    uint32_t p0 = P[i], p1 = P[i + 1];
    if (p1 > (uint32_t)Eg) p1 = Eg;
    if (p0 > p1) p0 = p1;
    float4v acc = (float4v){0.f, 0.f, 0.f, 0.f};
    if (h == 0) acc = *(const float4v*)(x + (size_t)i * 64 + t * 4);   // self loop
    uint32_t p = p0 + h;
    for (; p + 12 < p1; p += 16){
        int cA = (int)(Pay[p]      >> 18);
        int cB = (int)(Pay[p + 4]  >> 18);
        int cC = (int)(Pay[p + 8]  >> 18);
        int cD = (int)(Pay[p + 12] >> 18);
        float4v vA = *(const float4v*)(x + (size_t)cA * 64 + t * 4);
        float4v vB = *(const float4v*)(x + (size_t)cB * 64 + t * 4);
        float4v vC = *(const float4v*)(x + (size_t)cC * 64 + t * 4);
        float4v vD = *(const float4v*)(x + (size_t)cD * 64 + t * 4);
        acc[0] += (vA[0] + vB[0]) + (vC[0] + vD[0]);
        acc[1] += (vA[1] + vB[1]) + (vC[1] + vD[1]);
        acc[2] += (vA[2] + vB[2]) + (vC[2] + vD[2]);
        acc[3] += (vA[3] + vB[3]) + (vC[3] + vD[3]);
    }
    for (; p < p1; p += 4){
        int c = (int)(Pay[p] >> 18);
        float4v v = *(const float4v*)(x + (size_t)c * 64 + t * 4);
        acc[0] += v[0]; acc[1] += v[1]; acc[2] += v[2]; acc[3] += v[3];
    }
    #pragma unroll
    for (int j = 0; j < 4; ++j){
        acc[j] += __shfl_xor(acc[j], 16, 64);
        acc[j] += __shfl_xor(acc[j], 32, 64);
    }
    if (h == 0){
        float invc = 1.f / (float)(p1 - p0 + 1);
        float* dst = ws + OF_MEAN + (size_t)sign * NF + (size_t)i * 64 + t * 4;
        #pragma unroll
        for (int j = 0; j < 4; ++j) dst[j] = sane(acc[j] * invc);
    }
}

// pool: 8 groups x 8 lanes; lane covers f = t*4..t*4+3; 32 edges in flight
__device__ __forceinline__ void pool_role(int b, const void* __restrict__ efp,
                                          const void* __restrict__ efn,
                                          const uint32_t* __restrict__ iws,
                                          uint32_t fB, float* __restrict__ ws){
    int wid = threadIdx.x >> 6, lane = threadIdx.x & 63;
    int gw = b * 4 + wid;
    int g = gw / N, i = gw - g * N;
    const void* ef = (g < 2) ? efp : efn;
    const uint32_t* P   = iws + OI_PTR + (size_t)g * (N + 1);
    const uint32_t* Pay = iws + OI_PAY + (size_t)g * Eg;
    int h = lane >> 3, t = lane & 7;
    uint32_t p0 = P[i], p1 = P[i + 1];
    if (p1 > (uint32_t)Eg) p1 = Eg;
    if (p0 > p1) p0 = p1;
    float m0 = 0.f, m1 = 0.f, m2 = 0.f, m3 = 0.f;
    uint32_t p = p0 + h;
    if (fB){
        const float* E = (const float*)ef;
        for (; p + 24 < p1; p += 32){
            uint32_t eA = Pay[p]      & 0x3FFFFu, eB = Pay[p + 8]  & 0x3FFFFu;
            uint32_t eC = Pay[p + 16] & 0x3FFFFu, eD = Pay[p + 24] & 0x3FFFFu;
            float4v vA = *(const float4v*)(E + (size_t)eA * 32 + t * 4);
            float4v vB = *(const float4v*)(E + (size_t)eB * 32 + t * 4);
            float4v vC = *(const float4v*)(E + (size_t)eC * 32 + t * 4);
            float4v vD = *(const float4v*)(E + (size_t)eD * 32 + t * 4);
            m0 = fmaxf(m0, fmaxf(fmaxf(vA[0], vB[0]), fmaxf(vC[0], vD[0])));
            m1 = fmaxf(m1, fmaxf(fmaxf(vA[1], vB[1]), fmaxf(vC[1], vD[1])));
            m2 = fmaxf(m2, fmaxf(fmaxf(vA[2], vB[2]), fmaxf(vC[2], vD[2])));
            m3 = fmaxf(m3, fmaxf(fmaxf(vA[3], vB[3]), fmaxf(vC[3], vD[3])));
        }
        for (; p < p1; p += 8){
            uint32_t e = Pay[p] & 0x3FFFFu;
            float4v v = *(const float4v*)(E + (size_t)e * 32 + t * 4);
            m0 = fmaxf(m0, v[0]); m1 = fmaxf(m1, v[1]);
            m2 = fmaxf(m2, v[2]); m3 = fmaxf(m3, v[3]);
        }
    } else {
        const short* E = (const short*)ef;
        for (; p + 24 < p1; p += 32){
            uint32_t eA = Pay[p]      & 0x3FFFFu, eB = Pay[p + 8]  & 0x3FFFFu;
            uint32_t eC = Pay[p + 16] & 0x3FFFFu, eD = Pay[p + 24] & 0x3FFFFu;
            short4v vA = *(const short4v*)(E + (size_t)eA * 32 + t * 4);
            short4v vB = *(const short4v*)(E + (size_t)eB * 32 + t * 4);
            short4v vC = *(const short4v*)(E + (size_t)eC * 32 + t * 4);
            short4v vD = *(const short4v*)(E + (size_t)eD * 32 + t * 4);
            m0 = fmaxf(m0, fmaxf(fmaxf(bs2f(vA[0]), bs2f(vB[0])), fmaxf(bs2f(vC[0]), bs2f(vD[0]))));
            m1 = fmaxf(m1, fmaxf(fmaxf(bs2f(vA[1]), bs2f(vB[1])), fmaxf(bs2f(vC[1]), bs2f(vD[1]))));
            m2 = fmaxf(m2, fmaxf(fmaxf(bs2f(vA[2]), bs2f(vB[2])), fmaxf(bs2f(vC[2]), bs2f(vD[2]))));
            m3 = fmaxf(m3, fmaxf(fmaxf(bs2f(vA[3]), bs2f(vB[3])), fmaxf(bs2f(vC[3]), bs2f(vD[3]))));
        }
        for (; p < p1; p += 8){
            uint32_t e = Pay[p] & 0x3FFFFu;
            short4v v = *(const short4v*)(E + (size_t)e * 32 + t * 4);
            m0 = fmaxf(m0, bs2f(v[0])); m1 = fmaxf(m1, bs2f(v[1]));
            m2 = fmaxf(m2, bs2f(v[2])); m3 = fmaxf(m3, bs2f(v[3]));
        }
    }
    #pragma unroll
    for (int mk = 8; mk <= 32; mk <<= 1){
        m0 = fmaxf(m0, __shfl_xor(m0, mk, 64));
        m1 = fmaxf(m1, __shfl_xor(m1, mk, 64));
        m2 = fmaxf(m2, __shfl_xor(m2, mk, 64));
        m3 = fmaxf(m3, __shfl_xor(m3, mk, 64));
    }
    m0 = sane(m0); m1 = sane(m1); m2 = sane(m2); m3 = sane(m3);
    float ss = m0 * m0 + m1 * m1 + m2 * m2 + m3 * m3;
    ss += __shfl_xor(ss, 1, 64); ss += __shfl_xor(ss, 2, 64); ss += __shfl_xor(ss, 4, 64);
    float inv = 1.f / fmaxf(sqrtf(ss), 1e-12f);
    if (h == 0){
        float* dst = ws + OF_POOL + ((size_t)g * N + i) * 32 + t * 4;
        dst[0] = sane(m0 * inv); dst[1] = sane(m1 * inv);
        dst[2] = sane(m2 * inv); dst[3] = sane(m3 * inv);
    }
}

// corr: 8 groups x 8 lanes; 4-edge unroll (8 x 16B loads in flight);
// diagonal = slot p1. Plain stores into CO/CL (negated), no atomics.
__device__ __forceinline__ void corr_role(int b, const uint32_t* __restrict__ iws,
                                          const float* __restrict__ ws_ro,
                                          float* __restrict__ CO, float* __restrict__ CL){
    int wid = threadIdx.x >> 6, lane = threadIdx.x & 63;
    int gw = b * 4 + wid;
    int sg = gw >= N;
    int i = gw - sg * N;
    int h = lane >> 3, t = lane & 7;
    const bf* Qb = (const bf*)(ws_ro + OF_QKVB) + (size_t)(sg * 3) * NF;
    const short* Kb = (const short*)(Qb + NF);
    const short* Vb = Kb + NF;
    const int csr = sg ? 2 : 0;
    const uint32_t* Pp  = iws + OI_PTR + (size_t)csr * (N + 1);
    const uint32_t* Pay = iws + OI_PAY + (size_t)csr * Eg;
    uint32_t p0 = Pp[i], p1 = Pp[i + 1];
    if (p1 > (uint32_t)Eg) p1 = Eg;
    if (p0 > p1) p0 = p1;
    float qf[8];
    {
        short8 qv = *(const short8*)((const short*)Qb + (size_t)i * 64 + t * 8);
        #pragma unroll
        for (int j = 0; j < 8; ++j) qf[j] = bs2f(qv[j]);   // pre-scaled 0.125*log2e
    }
    float accO[8] = {0.f,0.f,0.f,0.f,0.f,0.f,0.f,0.f};
    float accL = 0.f;
    constexpr float C = 0.63212055882f;      // 1 - 1/e
    uint32_t p = p0 + h;
    // main: 4 slots {p, p+8, p+16, p+24}; only the last can be the diagonal
    for (; p + 24 <= p1; p += 32){
        int cA = (int)(Pay[p]      >> 18);
        int cB = (int)(Pay[p + 8]  >> 18);
        int cC = (int)(Pay[p + 16] >> 18);
        int cD = (p + 24 < p1) ? (int)(Pay[p + 24] >> 18) : i;
        short8 kvA = *(const short8*)(Kb + (size_t)cA * 64 + t * 8);
        short8 kvB = *(const short8*)(Kb + (size_t)cB * 64 + t * 8);
        short8 kvC = *(const short8*)(Kb + (size_t)cC * 64 + t * 8);
        short8 kvD = *(const short8*)(Kb + (size_t)cD * 64 + t * 8);
        short8 vvA = *(const short8*)(Vb + (size_t)cA * 64 + t * 8);
        short8 vvB = *(const short8*)(Vb + (size_t)cB * 64 + t * 8);
        short8 vvC = *(const short8*)(Vb + (size_t)cC * 64 + t * 8);
        short8 vvD = *(const short8*)(Vb + (size_t)cD * 64 + t * 8);
        float sA = qf[0] * bs2f(kvA[0]);
        float sB = qf[0] * bs2f(kvB[0]);
        float sC = qf[0] * bs2f(kvC[0]);
        float sD = qf[0] * bs2f(kvD[0]);
        #pragma unroll
        for (int j = 1; j < 8; ++j){
            sA += qf[j] * bs2f(kvA[j]); sB += qf[j] * bs2f(kvB[j]);
            sC += qf[j] * bs2f(kvC[j]); sD += qf[j] * bs2f(kvD[j]);
        }
        sA += __shfl_xor(sA, 1, 64); sB += __shfl_xor(sB, 1, 64);
        sC += __shfl_xor(sC, 1, 64); sD += __shfl_xor(sD, 1, 64);
        sA += __shfl_xor(sA, 2, 64); sB += __shfl_xor(sB, 2, 64);
        sC += __shfl_xor(sC, 2, 64); sD += __shfl_xor(sD, 2, 64);
        sA += __shfl_xor(sA, 4, 64); sB += __shfl_xor(sB, 4, 64);
        sC += __shfl_xor(sC, 4, 64); sD += __shfl_xor(sD, 4, 64);
        float fA = C * __builtin_amdgcn_exp2f(sA + L2E);
        float fB = C * __builtin_amdgcn_exp2f(sB + L2E);
        float fC = C * __builtin_amdgcn_exp2f(sC + L2E);
        float fD = C * __builtin_amdgcn_exp2f(sD + L2E);
        accL += (fA + fB) + (fC + fD);
        #pragma unroll
        for (int j = 0; j < 8; ++j)
            accO[j] += (fA * bs2f(vvA[j]) + fB * bs2f(vvB[j]))
                     + (fC * bs2f(vvC[j]) + fD * bs2f(vvD[j]));
    }
    for (; p <= p1; p += 8){
        int c = (p < p1) ? (int)(Pay[p] >> 18) : i;
        short8 kv = *(const short8*)(Kb + (size_t)c * 64 + t * 8);
        short8 vv = *(const short8*)(Vb + (size_t)c * 64 + t * 8);
        float s = qf[0] * bs2f(kv[0]);
        #pragma unroll
        for (int j = 1; j < 8; ++j) s += qf[j] * bs2f(kv[j]);
        s += __shfl_xor(s, 1, 64);
        s += __shfl_xor(s, 2, 64);
        s += __shfl_xor(s, 4, 64);
        float f = C * __builtin_amdgcn_exp2f(s + L2E);
        accL += f;
        #pragma unroll
        for (int j = 0; j < 8; ++j) accO[j] += f * bs2f(vv[j]);
    }
    #pragma unroll
    for (int j = 0; j < 8; ++j){
        accO[j] += __shfl_xor(accO[j], 8, 64);
        accO[j] += __shfl_xor(accO[j], 16, 64);
        accO[j] += __shfl_xor(accO[j], 32, 64);
    }
    accL += __shfl_xor(accL, 8, 64);
    accL += __shfl_xor(accL, 16, 64);
    accL += __shfl_xor(accL, 32, 64);
    if (h == 0){
        float* Op = CO + ((size_t)sg * N + i) * 64 + t * 8;
        #pragma unroll
        for (int j = 0; j < 8; ++j) Op[j] = -accO[j];
        if (t == 0) CL[(size_t)sg * N + i] = -accL;
    }
}

__global__ void mega_kernel(const void* __restrict__ efp, const void* __restrict__ efn,
                            const uint32_t* __restrict__ iws,
                            const uint32_t* __restrict__ flags, float* __restrict__ ws){
    int b = blockIdx.x;
    if (b < 3072)       mean_role(b, iws, ws, ws);
    else if (b < 9216)  pool_role(b - 3072, efp, efn, iws, flags[1], ws);
    else                corr_role(b - 9216, iws, ws, ws + OF_CO, ws + OF_CL);
}

// ---- dense attention role + CSR fill role fused ----
#define GLB1(p) ((const __attribute__((address_space(1))) void*)(p))
#define LDS3(p) ((__attribute__((address_space(3))) void*)(p))

__device__ __forceinline__ uint32_t lds_off32(const void* p){
    return (uint32_t)(uintptr_t)(__attribute__((address_space(3))) const void*)p;
}
__device__ __forceinline__ short8 ds_read_b128_off(uint32_t addr, int off){
    short8 r;
    asm volatile("ds_read_b128 %0, %1 offset:%2" : "=v"(r) : "v"(addr), "i"(off));
    return r;
}
__device__ __forceinline__ unsigned long long ds_tr16(uint32_t addr, int off){
    unsigned long long r;
    asm volatile("ds_read_b64_tr_b16 %0, %1 offset:%2" : "=v"(r) : "v"(addr), "i"(off));
    return r;
}
__device__ __forceinline__ unsigned cvt_pk_bf16(float lo, float hi){
    unsigned r;
    asm("v_cvt_pk_bf16_f32 %0, %1, %2" : "=v"(r) : "v"(lo), "v"(hi));
    return r;
}

__device__ void attn_role(int ab, short* lds_s, const bf* __restrict__ qkvb,
                          float* __restrict__ OP, float* __restrict__ LP){
    int tid = threadIdx.x, lane = tid & 63, wv = tid >> 6;
    int m16 = lane & 15, quad = lane >> 4;
    int rt = ab % 96, cs = (ab / 96) & 3, sg = ab / 384;
    const bf* Qb = qkvb + (size_t)(sg * 3) * NF;
    const bf* Kb = Qb + NF;
    const bf* Vb = Kb + NF;

    int rowbase = rt * 64 + wv * 16;
    short8 Qf0 = *(const short8*)(Qb + (size_t)(rowbase + m16) * 64 + quad * 8);
    short8 Qf1 = *(const short8*)(Qb + (size_t)(rowbase + m16) * 64 + 32 + quad * 8);

    float4v Oc[4];
    #pragma unroll
    for (int t = 0; t < 4; ++t) Oc[t] = (float4v){0.f, 0.f, 0.f, 0.f};
    float l = 0.f;

    const uint32_t lds0 = lds_off32(lds_s);

    auto stage = [&](int cb, int b){
        char* kdst = (char*)lds_s + b * 8192 + wv * 2048;
        char* vdst = (char*)lds_s + 16384 + b * 8192 + wv * 2048;
        #pragma unroll
        for (int inst = 0; inst < 2; ++inst){
            int Lb = wv * 2048 + inst * 1024 + lane * 16;   // dest byte in 8KB buf
            int cl = Lb >> 7;
            int gc = (cl & 32) | (((cl >> 2) & 3) << 3) | (((cl >> 4) & 1) << 2) | (cl & 3);
            int d2 = (Lb & 127) ^ ((cl & 7) << 4);
            const char* ksrc = (const char*)Kb + (((size_t)(cb + gc)) << 7) + d2;
            __builtin_amdgcn_global_load_lds(GLB1(ksrc), LDS3(kdst + inst * 1024), 16, 0, 0);
            int idx = Lb >> 1;
            int vc  = ((idx >> 8) << 2) | ((idx >> 4) & 3);
            int vd  = (((idx >> 6) & 3) << 4) | (idx & 8);
            const char* vsrc = (const char*)Vb + (((size_t)(cb + vc)) << 7) + (vd << 1);
            __builtin_amdgcn_global_load_lds(GLB1(vsrc), LDS3(vdst + inst * 1024), 16, 0, 0);
        }
    };

    const int sw16 = (m16 & 7) << 4;                 // K read swizzle (lane-const)
    const uint32_t kx0 = (uint32_t)(m16 * 128 + ((quad * 16) ^ sw16));
    const uint32_t kx1 = (uint32_t)(m16 * 128 + (((64 + quad * 16)) ^ sw16));
    const uint32_t vx  = (uint32_t)(quad * 1024 + m16 * 2);

    int c0 = cs * (N / 4), c1 = c0 + N / 4;
    stage(c0, 0);
    asm volatile("s_waitcnt vmcnt(0)" ::: "memory");
    __syncthreads();

    int buf = 0;
    for (int cb = c0; cb < c1; cb += 64){
        if (cb + 64 < c1) stage(cb + 64, buf ^ 1);   // prefetch next tile (other buf)
        uint32_t kb0 = lds0 + (uint32_t)(buf * 8192) + kx0;
        uint32_t kb1 = lds0 + (uint32_t)(buf * 8192) + kx1;
        uint32_t vab = lds0 + 16384u + (uint32_t)(buf * 8192) + vx;
        #pragma unroll
        for (int kg = 0; kg < 2; ++kg){
            short8 A[2][2];
            #pragma unroll
            for (int ct = 0; ct < 2; ++ct){
                A[ct][0] = ds_read_b128_off(kb0, kg * 4096 + ct * 2048);
                A[ct][1] = ds_read_b128_off(kb1, kg * 4096 + ct * 2048);
            }
            unsigned long long tr[8];
            #pragma unroll
            for (int dt = 0; dt < 4; ++dt)
                #pragma unroll
                for (int w = 0; w < 2; ++w)
                    tr[dt * 2 + w] = ds_tr16(vab, kg * 4096 + w * 512 + dt * 128);
            asm volatile("s_waitcnt lgkmcnt(8)" ::: "memory");  // K frags done
            __builtin_amdgcn_sched_barrier(0);
            float4v s0 = __builtin_amdgcn_mfma_f32_16x16x32_bf16(
                             A[0][0], Qf0, (float4v){0.f,0.f,0.f,0.f}, 0, 0, 0);
            s0 = __builtin_amdgcn_mfma_f32_16x16x32_bf16(A[0][1], Qf1, s0, 0, 0, 0);
            float4v s1 = __builtin_amdgcn_mfma_f32_16x16x32_bf16(
                             A[1][0], Qf0, (float4v){0.f,0.f,0.f,0.f}, 0, 0, 0);
            s1 = __builtin_amdgcn_mfma_f32_16x16x32_bf16(A[1][1], Qf1, s1, 0, 0, 0);
            float p0[4], p1[4];
            #pragma unroll
            for (int r = 0; r < 4; ++r){
                p0[r] = __builtin_amdgcn_exp2f(s0[r] + L2E);
                p1[r] = __builtin_amdgcn_exp2f(s1[r] + L2E);
                l += p0[r] + p1[r];
            }
            union { unsigned u[4]; short8 s8; } pf;
            pf.u[0] = cvt_pk_bf16(p0[0], p0[1]);
            pf.u[1] = cvt_pk_bf16(p0[2], p0[3]);
            pf.u[2] = cvt_pk_bf16(p1[0], p1[1]);
            pf.u[3] = cvt_pk_bf16(p1[2], p1[3]);
            asm volatile("s_waitcnt lgkmcnt(0)" ::: "memory");  // tr reads done
            __builtin_amdgcn_sched_barrier(0);
            #pragma unroll
            for (int dt = 0; dt < 4; ++dt){
                union { unsigned long long u[2]; short8 s8; } va;
                va.u[0] = tr[dt * 2];
                va.u[1] = tr[dt * 2 + 1];
                Oc[dt] = __builtin_amdgcn_mfma_f32_16x16x32_bf16(va.s8, pf.s8, Oc[dt], 0, 0, 0);
            }
        }
        asm volatile("s_waitcnt vmcnt(0)" ::: "memory");  // prefetch landed
        __syncthreads();                                   // all waves done with buf
        buf ^= 1;
    }

    l += __shfl_xor(l, 16, 64);
    l += __shfl_xor(l, 32, 64);
    int slab = cs * 2 + sg;
    if (quad == 0) LP[(size_t)slab * N + rowbase + m16] = l;
    float* Op = OP + ((size_t)slab * N + rowbase + m16) * 64;
    #pragma unroll
    for (int dt = 0; dt < 4; ++dt)
        *(float4v*)(Op + dt * 16 + quad * 4) = Oc[dt];
}

// Round 9: launch_bounds back to (256,3) — R8's (256,5) regressed (+5 us);
// attn grid is 3 blocks/CU anyway, the cap change only perturbed scheduling.
__global__ void __launch_bounds__(256, 3)
attn_fill_kernel(const int* __restrict__ eip, const int* __restrict__ ein,
                 uint32_t* __restrict__ iws, const bf* __restrict__ qkvb,
                 float* __restrict__ OP, float* __restrict__ LP){
    __shared__ __align__(16) short lds_s[16384];   // 32 KiB (attn role only)
    int b = blockIdx.x;
    if (b < 768){
        attn_role(b, lds_s, qkvb, OP, LP);
        return;
    }
    int e = (b - 768) * 256 + threadIdx.x;
    if (e >= Eg) return;
    uint32_t* Cu  = iws + OI_CUR;
    uint32_t* Pay = iws + OI_PAY;
    int rp = clampi(eip[e]), cp = clampi(eip[Eg + e]);
    int rn = clampi(ein[e]), cn = clampi(ein[Eg + e]);
    uint32_t p;
    p = atomicAdd(&Cu[0 * N + rp], 1u); if (p < Eg) Pay[0 * (size_t)Eg + p] = (uint32_t)e | ((uint32_t)cp << 18);
    p = atomicAdd(&Cu[1 * N + cp], 1u); if (p < Eg) Pay[1 * (size_t)Eg + p] = (uint32_t)e | ((uint32_t)rp << 18);
    p = atomicAdd(&Cu[2 * N + rn], 1u); if (p < Eg) Pay[2 * (size_t)Eg + p] = (uint32_t)e | ((uint32_t)cn << 18);
    p = atomicAdd(&Cu[3 * N + cn], 1u); if (p < Eg) Pay[3 * (size_t)Eg + p] = (uint32_t)e | ((uint32_t)rn << 18);
}

// final: 4 rows/wave in registers, readlane broadcast, W streamed once/wave.
// O/l assembled from 4 attn partials + corr buffer (no atomics upstream).
__global__ void final_kernel(const uint32_t* __restrict__ flags,
                             const float* __restrict__ ws, void* __restrict__ outv){
    uint32_t fA = flags[0];
    int t = threadIdx.x, lane = t & 63, wv = t >> 6;
    int row0 = blockIdx.x * 16 + wv * 4;
    float fr[6][4];
    #pragma unroll
    for (int s = 0; s < 2; ++s){
        float onr[4];
        #pragma unroll
        for (int r = 0; r < 4; ++r){
            int i = row0 + r;
            float osum = ws[OF_CO + ((size_t)s * N + i) * 64 + lane];
            float lsum = ws[OF_CL + (size_t)s * N + i];
            #pragma unroll
            for (int cs = 0; cs < 4; ++cs){
                int slab = cs * 2 + s;
                osum += ws[OF_OP + ((size_t)slab * N + i) * 64 + lane];
                lsum += ws[OF_LP + (size_t)slab * N + i];
            }
            onr[r] = sane(osum / fmaxf(lsum, 1e-20f));
        }
        const float* Wo = ws + OF_WO + (size_t)s * 4096;
        float b0 = ws[OF_BO + s * 64 + lane];
        float a[4] = {b0, b0, b0, b0};
        #pragma unroll 16
        for (int d = 0; d < 64; ++d){
            float w = Wo[d * 64 + lane];
            a[0] += rl(onr[0], d) * w;
            a[1] += rl(onr[1], d) * w;
            a[2] += rl(onr[2], d) * w;
            a[3] += rl(onr[3], d) * w;
        }
        #pragma unroll
        for (int r = 0; r < 4; ++r){
            int i = row0 + r;
            float mean = ws[OF_MEAN + (size_t)s * NF + (size_t)i * 64 + lane];
            fr[s][r] = sane(mean + a[r]);
        }
    }
    {
        int g0 = lane >> 5, f = lane & 31;
        #pragma unroll
        for (int r = 0; r < 4; ++r){
            int i = row0 + r;
            fr[2][r] = ws[OF_XF + (size_t)i * 64 + lane];
            fr[3][r] = ws[OF_XF + NF + (size_t)i * 64 + lane];
            fr[4][r] = ws[OF_POOL + ((size_t)g0 * N + i) * 32 + f];
            fr[5][r] = ws[OF_POOL + ((size_t)(2 + g0) * N + i) * 32 + f];
        }
    }
    const float* WF = ws + OF_WF;
    float bf0 = ws[OF_BF + lane];
    float acc[4] = {bf0, bf0, bf0, bf0};
    #pragma unroll
    for (int j = 0; j < 6; ++j){
        #pragma unroll 16
        for (int dd = 0; dd < 64; ++dd){
            float w = WF[(size_t)(j * 64 + dd) * 64 + lane];
            acc[0] += rl(fr[j][0], dd) * w;
            acc[1] += rl(fr[j][1], dd) * w;
            acc[2] += rl(fr[j][2], dd) * w;
            acc[3] += rl(fr[j][3], dd) * w;
        }
    }
    #pragma unroll
    for (int r = 0; r < 4; ++r){
        float a = sane(acc[r]);
        float ss = a * a;
        ss += __shfl_xor(ss, 32, 64); ss += __shfl_xor(ss, 16, 64); ss += __shfl_xor(ss, 8, 64);
        ss += __shfl_xor(ss, 4, 64);  ss += __shfl_xor(ss, 2, 64);  ss += __shfl_xor(ss, 1, 64);
        float out = a / fmaxf(sqrtf(ss), 1e-12f);
        int i = row0 + r;
        if (fA) ((float*)outv)[(size_t)i * 64 + lane] = out;
        else    ((bf*)outv)[(size_t)i * 64 + lane] = __float2bfloat16(out);
    }
}

extern "C" void kernel_launch(void* const* d_in, const int* in_sizes, int n_in,
                              void* d_out, int out_size, void* d_ws, size_t ws_size,
                              hipStream_t stream){
    const int* eip = (const int*)d_in[2];
    const int* ein = (const int*)d_in[3];

    float* ws = (float*)d_ws;
    uint32_t* iws = (uint32_t*)(ws + F_TOTAL);
    uint32_t* flags = iws + OI_FLAG;
    bf* qkvb = (bf*)(ws + OF_QKVB);

    int nu = 4 * N;                        // CSR counts
    zero_sniff_kernel<<<dim3((nu + 255) / 256), 256, 0, stream>>>(
        iws + OI_CNT, nu, d_in[0], d_in[4], d_in[6], d_in[8], flags);
    convert_kernel<<<dim3(3072, 4), 256, 0, stream>>>(
        d_in[0], d_in[1],
        d_in[8],  d_in[10], d_in[12], d_in[16], d_in[18], d_in[20],
        d_in[9],  d_in[11], d_in[13], d_in[17], d_in[19], d_in[21],
        d_in[14], d_in[15], d_in[22], d_in[23],
        d_in[6],  d_in[7],
        eip, ein, iws,
        flags, ws);
    scan_qkv_kernel<<<dim3(4 + 2304), 256, 0, stream>>>(iws, ws, ws);
    attn_fill_kernel<<<dim3(768 + 768), 256, 0, stream>>>(
        eip, ein, iws, qkvb, ws + OF_OP, ws + OF_LP);
    mega_kernel<<<dim3(12288), 256, 0, stream>>>(d_in[4], d_in[5], iws, flags, ws);
    final_kernel<<<dim3(N / 16), 256, 0, stream>>>(flags, ws, d_out);
}

// Round 11
// 187.936 us; speedup vs baseline: 1.0225x; 1.0149x over previous
//
#include <hip/hip_runtime.h>
#include <hip/hip_bf16.h>
#include <stdint.h>

typedef __hip_bfloat16 bf;
typedef __attribute__((ext_vector_type(8))) short short8;
typedef __attribute__((ext_vector_type(4))) short short4v;
typedef __attribute__((ext_vector_type(4))) float float4v;
__device__ __forceinline__ float b2f(bf x){ return __bfloat162float(x); }
__device__ __forceinline__ float bs2f(short s){
    return __uint_as_float(((uint32_t)(uint16_t)s) << 16);
}
__device__ __forceinline__ float sane(float x){ return fminf(fmaxf(x, -1e6f), 1e6f); }
__device__ __forceinline__ float rl(float v, int l){
    return __int_as_float(__builtin_amdgcn_readlane(__float_as_int(v), l));
}

// Problem constants
constexpr int N   = 6144;          // NOT a power of two (3*2^11)!
constexpr int D   = 64;
constexpr int FE  = 32;
constexpr int Eg  = 196608;        // < 2^18 -> edge id packs in 18 bits
constexpr size_t NF = (size_t)N * D;

constexpr float L2E = 1.4426950408889634f;   // log2(e)

__device__ __forceinline__ int clampi(int v){ return v < 0 ? 0 : (v >= N ? N - 1 : v); }
__device__ __forceinline__ float ldf(const void* p, size_t i, uint32_t isf32){
    return isf32 ? ((const float*)p)[i] : b2f(((const bf*)p)[i]);
}

// ---- float workspace layout (floats) ----  ~30.4 MB
constexpr size_t OF_OP   = 0;                           // [4][2][N][D] attn partial O
constexpr size_t OF_LP   = OF_OP + 8*NF;                // [4][2][N]    attn partial L
constexpr size_t OF_CO   = OF_LP + 8*(size_t)N;         // [2][N][D]    corr O (negative)
constexpr size_t OF_CL   = OF_CO + 2*NF;                // [2][N]       corr L (negative)
constexpr size_t OF_MEAN = OF_CL + 2*(size_t)N;         // [2][N][D]
constexpr size_t OF_POOL = OF_MEAN + 2*NF;              // [4][N][FE]
constexpr size_t OF_QKVB = OF_POOL + (size_t)4*N*FE;    // bf16 [2][3][N][D] (Q pre-scaled)
constexpr size_t OF_XF   = OF_QKVB + 3*NF;              // [2][N][D] f32 staged x1,x2
constexpr size_t OF_WA   = OF_XF + 2*NF;                // [6][64][64] attn proj W (f32)
constexpr size_t OF_BA   = OF_WA + 24576;               // [6][64]
constexpr size_t OF_WO   = OF_BA + 384;                 // [2][64][64] Wo_p, Wo_n
constexpr size_t OF_BO   = OF_WO + 8192;                // [2][64]
constexpr size_t OF_WF   = OF_BO + 128;                 // [384][64] final weight
constexpr size_t OF_BF   = OF_WF + 24576;               // [64]
constexpr size_t F_TOTAL = OF_BF + 64;
// ---- u32 workspace (words, after float region) ----  ~3.44 MB
constexpr size_t OI_CNT  = 0;                           // [4][N]
constexpr size_t OI_PTR  = OI_CNT + 4*(size_t)N;        // [4][N+1]
constexpr size_t OI_CUR  = OI_PTR + 4*(size_t)(N+1);    // [4][N]
constexpr size_t OI_PAY  = OI_CUR + 4*(size_t)N;        // [4][Eg]  payload: e | (other<<18)
constexpr size_t OI_FLAG = OI_PAY + 4*(size_t)Eg;       // [4] dtype flags

// zero CSR counts + dtype-sniff fused (last 4 blocks sniff one tensor each).
__global__ void zero_sniff_kernel(uint32_t* __restrict__ uz, int nu,
                                  const void* xA, const void* xB,
                                  const void* xC, const void* xD,
                                  uint32_t* __restrict__ flags){
    int i = blockIdx.x * 256 + threadIdx.x;
    if (i < nu) uz[i] = 0u;
    int sb = (int)gridDim.x - 4;
    if (blockIdx.x >= sb){
        int k = blockIdx.x - sb;
        const void* ps[4] = {xA, xB, xC, xD};
        const bf* p = (const bf*)ps[k];
        __shared__ float red[256];
        int t = threadIdx.x;
        float m = 0.f;
        for (int j = t; j < 1024; j += 256){
            float v = fabsf(b2f(p[j]));
            if (!(v <= 1e9f)) v = 1e9f;
            m = fmaxf(m, v);
        }
        red[t] = m; __syncthreads();
        for (int off = 128; off; off >>= 1){
            if (t < off) red[t] = fmaxf(red[t], red[t + off]);
            __syncthreads();
        }
        if (t == 0) flags[k] = (red[0] > 100.f) ? 1u : 0u;
    }
}

// convert float tensors to f32 staging + CSR count fused (y==3)
__global__ void convert_kernel(const void* x1, const void* x2,
                               const void* W0, const void* W1, const void* W2,
                               const void* W3, const void* W4, const void* W5,
                               const void* B0, const void* B1, const void* B2,
                               const void* B3, const void* B4, const void* B5,
                               const void* Wop, const void* bop,
                               const void* Won, const void* bon,
                               const void* wgt, const void* bia,
                               const int* __restrict__ eip, const int* __restrict__ ein,
                               uint32_t* __restrict__ iws,
                               const uint32_t* __restrict__ flags, float* __restrict__ ws){
    int y = blockIdx.y;
    size_t idx = (size_t)blockIdx.x * 256 + threadIdx.x;
    if (y == 0){
        uint32_t fA = flags[0];
        float v = (idx < NF) ? ldf(x1, idx, fA) : ldf(x2, idx - NF, fA);
        ws[OF_XF + idx] = sane(v);
    } else if (y == 1){
        if (idx >= 33280) return;
        uint32_t fD = flags[3];
        float v;
        if (idx < 24576){
            int m = (int)(idx >> 12), sub = (int)(idx & 4095);
            const void* W = (m==0)?W0:(m==1)?W1:(m==2)?W2:(m==3)?W3:(m==4)?W4:W5;
            v = ldf(W, sub, fD);
        } else if (idx < 24960){
            int m = (int)((idx - 24576) >> 6), sub = (int)(idx & 63);
            const void* B = (m==0)?B0:(m==1)?B1:(m==2)?B2:(m==3)?B3:(m==4)?B4:B5;
            v = ldf(B, sub, fD);
        } else if (idx < 33152){
            int k = (int)((idx - 24960) >> 12), sub = (int)(idx & 4095);
            v = ldf(k ? Won : Wop, sub, fD);
        } else {
            int k = (int)((idx - 33152) >> 6), sub = (int)(idx & 63);
            v = ldf(k ? bon : bop, sub, fD);
        }
        ws[OF_WA + idx] = sane(v);
    } else if (y == 2){
        if (idx >= 24640) return;
        uint32_t fC = flags[2];
        float v = (idx < 24576) ? ldf(wgt, idx, fC) : ldf(bia, idx - 24576, fC);
        ws[OF_WF + idx] = sane(v);
    } else {
        // CSR count (only first 768 x-blocks carry edges)
        if (idx >= (size_t)Eg) return;
        int e = (int)idx;
        uint32_t* cnt = iws + OI_CNT;
        atomicAdd(&cnt[0 * N + clampi(eip[e])],      1u);
        atomicAdd(&cnt[1 * N + clampi(eip[Eg + e])], 1u);
        atomicAdd(&cnt[2 * N + clampi(ein[e])],      1u);
        atomicAdd(&cnt[3 * N + clampi(ein[Eg + e])], 1u);
    }
}

// ---- scan + qkv fused: blocks 0..3 = CSR exclusive scan; rest = qkv ----
__device__ __forceinline__ void scan_role(int b, uint32_t* __restrict__ iws){
    int t = threadIdx.x;
    const uint32_t* c = iws + OI_CNT + (size_t)b * N;
    uint32_t* P  = iws + OI_PTR + (size_t)b * (N + 1);
    uint32_t* Cu = iws + OI_CUR + (size_t)b * N;
    constexpr int K = N / 256;
    int base = t * K;
    uint32_t s = 0;
    for (int k = 0; k < K; ++k) s += c[base + k];
    __shared__ uint32_t sums[256];
    sums[t] = s; __syncthreads();
    for (int off = 1; off < 256; off <<= 1){
        uint32_t v = (t >= off) ? sums[t - off] : 0u;
        __syncthreads();
        sums[t] += v;
        __syncthreads();
    }
    uint32_t run = (t == 0) ? 0u : sums[t - 1];
    for (int k = 0; k < K; ++k){ P[base + k] = run; Cu[base + k] = run; run += c[base + k]; }
    if (t == 255) P[N] = run;
}

__device__ __forceinline__ void qkv_role(int q, const float* __restrict__ ws_ro,
                                         float* __restrict__ ws){
    int m = q / 384, xb = q - m * 384;
    int t = threadIdx.x, lane = t & 63, wv = t >> 6;
    int row0 = xb * 16 + wv * 4;
    const float* x = ws_ro + OF_XF + (m < 3 ? 0 : NF) + (size_t)row0 * 64;
    const float* W = ws_ro + OF_WA + (size_t)m * 4096;
    float x0 = x[lane], x1 = x[64 + lane], x2 = x[128 + lane], x3 = x[192 + lane];
    float bbias = ws_ro[OF_BA + m * 64 + lane];
    float a0 = bbias, a1 = bbias, a2 = bbias, a3 = bbias;
    #pragma unroll 16
    for (int d = 0; d < 64; ++d){
        float w = W[d * 64 + lane];
        a0 += rl(x0, d) * w;
        a1 += rl(x1, d) * w;
        a2 += rl(x2, d) * w;
        a3 += rl(x3, d) * w;
    }
    float sc = (m == 0 || m == 3) ? 0.125f * L2E : 1.f;
    bf* qkvb = (bf*)(ws + OF_QKVB) + (size_t)m * NF + (size_t)row0 * 64;
    qkvb[lane]       = __float2bfloat16(sane(a0) * sc);
    qkvb[64 + lane]  = __float2bfloat16(sane(a1) * sc);
    qkvb[128 + lane] = __float2bfloat16(sane(a2) * sc);
    qkvb[192 + lane] = __float2bfloat16(sane(a3) * sc);
}

__global__ void scan_qkv_kernel(uint32_t* __restrict__ iws,
                                const float* __restrict__ ws_ro, float* __restrict__ ws){
    int b = blockIdx.x;
    if (b < 4) scan_role(b, iws);
    else       qkv_role(b - 4, ws_ro, ws);
}

// ---- mega kernel roles (R7 config: 2-edge unrolled gathers) ----
// R10 post-mortem: 4-edge unroll cut occupancy 65->41% (VGPR pressure) and
// was net-negative in this latency-bound regime. Reverted to 2-edge.

// mean: 4 groups x 16 lanes; lane covers d = t*4..t*4+3 (float4 gathers)
__device__ __forceinline__ void mean_role(int b, const uint32_t* __restrict__ iws,
                                          const float* __restrict__ ws_ro, float* __restrict__ ws){
    int wid = threadIdx.x >> 6, lane = threadIdx.x & 63;
    int gw = b * 4 + wid;
    int sign = gw >= N;
    int i = gw - sign * N;
    int h = lane >> 4, t = lane & 15;
    const float* x = ws_ro + OF_XF + (size_t)sign * NF;
    int csr = sign ? 2 : 0;
    const uint32_t* P   = iws + OI_PTR + (size_t)csr * (N + 1);
    const uint32_t* Pay = iws + OI_PAY + (size_t)csr * Eg;
    uint32_t p0 = P[i], p1 = P[i + 1];
    if (p1 > (uint32_t)Eg) p1 = Eg;
    if (p0 > p1) p0 = p1;
    float4v acc = (float4v){0.f, 0.f, 0.f, 0.f};
    if (h == 0) acc = *(const float4v*)(x + (size_t)i * 64 + t * 4);   // self loop
    uint32_t p = p0 + h;
    for (; p + 4 < p1; p += 8){
        int cA = (int)(Pay[p] >> 18);
        int cB = (int)(Pay[p + 4] >> 18);
        float4v vA = *(const float4v*)(x + (size_t)cA * 64 + t * 4);
        float4v vB = *(const float4v*)(x + (size_t)cB * 64 + t * 4);
        acc[0] += vA[0] + vB[0]; acc[1] += vA[1] + vB[1];
        acc[2] += vA[2] + vB[2]; acc[3] += vA[3] + vB[3];
    }
    if (p < p1){
        int c = (int)(Pay[p] >> 18);
        float4v v = *(const float4v*)(x + (size_t)c * 64 + t * 4);
        acc[0] += v[0]; acc[1] += v[1]; acc[2] += v[2]; acc[3] += v[3];
    }
    #pragma unroll
    for (int j = 0; j < 4; ++j){
        acc[j] += __shfl_xor(acc[j], 16, 64);
        acc[j] += __shfl_xor(acc[j], 32, 64);
    }
    if (h == 0){
        float invc = 1.f / (float)(p1 - p0 + 1);
        float* dst = ws + OF_MEAN + (size_t)sign * NF + (size_t)i * 64 + t * 4;
        #pragma unroll
        for (int j = 0; j < 4; ++j) dst[j] = sane(acc[j] * invc);
    }
}

// pool: 8 groups x 8 lanes; lane covers f = t*4..t*4+3; 16 edges in flight
__device__ __forceinline__ void pool_role(int b, const void* __restrict__ efp,
                                          const void* __restrict__ efn,
                                          const uint32_t* __restrict__ iws,
                                          uint32_t fB, float* __restrict__ ws){
    int wid = threadIdx.x >> 6, lane = threadIdx.x & 63;
    int gw = b * 4 + wid;
    int g = gw / N, i = gw - g * N;
    const void* ef = (g < 2) ? efp : efn;
    const uint32_t* P   = iws + OI_PTR + (size_t)g * (N + 1);
    const uint32_t* Pay = iws + OI_PAY + (size_t)g * Eg;
    int h = lane >> 3, t = lane & 7;
    uint32_t p0 = P[i], p1 = P[i + 1];
    if (p1 > (uint32_t)Eg) p1 = Eg;
    if (p0 > p1) p0 = p1;
    float m0 = 0.f, m1 = 0.f, m2 = 0.f, m3 = 0.f;
    uint32_t p = p0 + h;
    if (fB){
        const float* E = (const float*)ef;
        for (; p + 8 < p1; p += 16){
            uint32_t eA = Pay[p] & 0x3FFFFu, eB = Pay[p + 8] & 0x3FFFFu;
            float4v vA = *(const float4v*)(E + (size_t)eA * 32 + t * 4);
            float4v vB = *(const float4v*)(E + (size_t)eB * 32 + t * 4);
            m0 = fmaxf(m0, fmaxf(vA[0], vB[0])); m1 = fmaxf(m1, fmaxf(vA[1], vB[1]));
            m2 = fmaxf(m2, fmaxf(vA[2], vB[2])); m3 = fmaxf(m3, fmaxf(vA[3], vB[3]));
        }
        if (p < p1){
            uint32_t e = Pay[p] & 0x3FFFFu;
            float4v v = *(const float4v*)(E + (size_t)e * 32 + t * 4);
            m0 = fmaxf(m0, v[0]); m1 = fmaxf(m1, v[1]);
            m2 = fmaxf(m2, v[2]); m3 = fmaxf(m3, v[3]);
        }
    } else {
        const short* E = (const short*)ef;
        for (; p + 8 < p1; p += 16){
            uint32_t eA = Pay[p] & 0x3FFFFu, eB = Pay[p + 8] & 0x3FFFFu;
            short4v vA = *(const short4v*)(E + (size_t)eA * 32 + t * 4);
            short4v vB = *(const short4v*)(E + (size_t)eB * 32 + t * 4);
            m0 = fmaxf(m0, fmaxf(bs2f(vA[0]), bs2f(vB[0])));
            m1 = fmaxf(m1, fmaxf(bs2f(vA[1]), bs2f(vB[1])));
            m2 = fmaxf(m2, fmaxf(bs2f(vA[2]), bs2f(vB[2])));
            m3 = fmaxf(m3, fmaxf(bs2f(vA[3]), bs2f(vB[3])));
        }
        if (p < p1){
            uint32_t e = Pay[p] & 0x3FFFFu;
            short4v v = *(const short4v*)(E + (size_t)e * 32 + t * 4);
            m0 = fmaxf(m0, bs2f(v[0])); m1 = fmaxf(m1, bs2f(v[1]));
            m2 = fmaxf(m2, bs2f(v[2])); m3 = fmaxf(m3, bs2f(v[3]));
        }
    }
    #pragma unroll
    for (int mk = 8; mk <= 32; mk <<= 1){
        m0 = fmaxf(m0, __shfl_xor(m0, mk, 64));
        m1 = fmaxf(m1, __shfl_xor(m1, mk, 64));
        m2 = fmaxf(m2, __shfl_xor(m2, mk, 64));
        m3 = fmaxf(m3, __shfl_xor(m3, mk, 64));
    }
    m0 = sane(m0); m1 = sane(m1); m2 = sane(m2); m3 = sane(m3);
    float ss = m0 * m0 + m1 * m1 + m2 * m2 + m3 * m3;
    ss += __shfl_xor(ss, 1, 64); ss += __shfl_xor(ss, 2, 64); ss += __shfl_xor(ss, 4, 64);
    float inv = 1.f / fmaxf(sqrtf(ss), 1e-12f);
    if (h == 0){
        float* dst = ws + OF_POOL + ((size_t)g * N + i) * 32 + t * 4;
        dst[0] = sane(m0 * inv); dst[1] = sane(m1 * inv);
        dst[2] = sane(m2 * inv); dst[3] = sane(m3 * inv);
    }
}

// corr: 8 groups x 8 lanes; 2-edge unroll; diagonal = slot p1.
// Plain stores into CO/CL (negated), no atomics.
__device__ __forceinline__ void corr_role(int b, const uint32_t* __restrict__ iws,
                                          const float* __restrict__ ws_ro,
                                          float* __restrict__ CO, float* __restrict__ CL){
    int wid = threadIdx.x >> 6, lane = threadIdx.x & 63;
    int gw = b * 4 + wid;
    int sg = gw >= N;
    int i = gw - sg * N;
    int h = lane >> 3, t = lane & 7;
    const bf* Qb = (const bf*)(ws_ro + OF_QKVB) + (size_t)(sg * 3) * NF;
    const short* Kb = (const short*)(Qb + NF);
    const short* Vb = Kb + NF;
    const int csr = sg ? 2 : 0;
    const uint32_t* Pp  = iws + OI_PTR + (size_t)csr * (N + 1);
    const uint32_t* Pay = iws + OI_PAY + (size_t)csr * Eg;
    uint32_t p0 = Pp[i], p1 = Pp[i + 1];
    if (p1 > (uint32_t)Eg) p1 = Eg;
    if (p0 > p1) p0 = p1;
    float qf[8];
    {
        short8 qv = *(const short8*)((const short*)Qb + (size_t)i * 64 + t * 8);
        #pragma unroll
        for (int j = 0; j < 8; ++j) qf[j] = bs2f(qv[j]);   // pre-scaled 0.125*log2e
    }
    float accO[8] = {0.f,0.f,0.f,0.f,0.f,0.f,0.f,0.f};
    float accL = 0.f;
    constexpr float C = 0.63212055882f;      // 1 - 1/e
    uint32_t p = p0 + h;
    for (; p + 8 <= p1; p += 16){
        int cA = (int)(Pay[p] >> 18);
        int cB = (p + 8 < p1) ? (int)(Pay[p + 8] >> 18) : i;
        short8 kvA = *(const short8*)(Kb + (size_t)cA * 64 + t * 8);
        short8 kvB = *(const short8*)(Kb + (size_t)cB * 64 + t * 8);
        short8 vvA = *(const short8*)(Vb + (size_t)cA * 64 + t * 8);
        short8 vvB = *(const short8*)(Vb + (size_t)cB * 64 + t * 8);
        float sA = qf[0] * bs2f(kvA[0]);
        float sB = qf[0] * bs2f(kvB[0]);
        #pragma unroll
        for (int j = 1; j < 8; ++j){ sA += qf[j] * bs2f(kvA[j]); sB += qf[j] * bs2f(kvB[j]); }
        sA += __shfl_xor(sA, 1, 64); sB += __shfl_xor(sB, 1, 64);
        sA += __shfl_xor(sA, 2, 64); sB += __shfl_xor(sB, 2, 64);
        sA += __shfl_xor(sA, 4, 64); sB += __shfl_xor(sB, 4, 64);
        float fA = C * __builtin_amdgcn_exp2f(sA + L2E);
        float fB = C * __builtin_amdgcn_exp2f(sB + L2E);
        accL += fA + fB;
        #pragma unroll
        for (int j = 0; j < 8; ++j) accO[j] += fA * bs2f(vvA[j]) + fB * bs2f(vvB[j]);
    }
    if (p <= p1){
        int c = (p < p1) ? (int)(Pay[p] >> 18) : i;
        short8 kv = *(const short8*)(Kb + (size_t)c * 64 + t * 8);
        short8 vv = *(const short8*)(Vb + (size_t)c * 64 + t * 8);
        float s = qf[0] * bs2f(kv[0]);
        #pragma unroll
        for (int j = 1; j < 8; ++j) s += qf[j] * bs2f(kv[j]);
        s += __shfl_xor(s, 1, 64);
        s += __shfl_xor(s, 2, 64);
        s += __shfl_xor(s, 4, 64);
        float f = C * __builtin_amdgcn_exp2f(s + L2E);
        accL += f;
        #pragma unroll
        for (int j = 0; j < 8; ++j) accO[j] += f * bs2f(vv[j]);
    }
    #pragma unroll
    for (int j = 0; j < 8; ++j){
        accO[j] += __shfl_xor(accO[j], 8, 64);
        accO[j] += __shfl_xor(accO[j], 16, 64);
        accO[j] += __shfl_xor(accO[j], 32, 64);
    }
    accL += __shfl_xor(accL, 8, 64);
    accL += __shfl_xor(accL, 16, 64);
    accL += __shfl_xor(accL, 32, 64);
    if (h == 0){
        float* Op = CO + ((size_t)sg * N + i) * 64 + t * 8;
        #pragma unroll
        for (int j = 0; j < 8; ++j) Op[j] = -accO[j];
        if (t == 0) CL[(size_t)sg * N + i] = -accL;
    }
}

__global__ void mega_kernel(const void* __restrict__ efp, const void* __restrict__ efn,
                            const uint32_t* __restrict__ iws,
                            const uint32_t* __restrict__ flags, float* __restrict__ ws){
    int b = blockIdx.x;
    if (b < 3072)       mean_role(b, iws, ws, ws);
    else if (b < 9216)  pool_role(b - 3072, efp, efn, iws, flags[1], ws);
    else                corr_role(b - 9216, iws, ws, ws + OF_CO, ws + OF_CL);
}

// ---- dense attention role + CSR fill role fused ----
#define GLB1(p) ((const __attribute__((address_space(1))) void*)(p))
#define LDS3(p) ((__attribute__((address_space(3))) void*)(p))

__device__ __forceinline__ uint32_t lds_off32(const void* p){
    return (uint32_t)(uintptr_t)(__attribute__((address_space(3))) const void*)p;
}
__device__ __forceinline__ short8 ds_read_b128_off(uint32_t addr, int off){
    short8 r;
    asm volatile("ds_read_b128 %0, %1 offset:%2" : "=v"(r) : "v"(addr), "i"(off));
    return r;
}
__device__ __forceinline__ unsigned long long ds_tr16(uint32_t addr, int off){
    unsigned long long r;
    asm volatile("ds_read_b64_tr_b16 %0, %1 offset:%2" : "=v"(r) : "v"(addr), "i"(off));
    return r;
}
__device__ __forceinline__ unsigned cvt_pk_bf16(float lo, float hi){
    unsigned r;
    asm("v_cvt_pk_bf16_f32 %0, %1, %2" : "=v"(r) : "v"(lo), "v"(hi));
    return r;
}

__device__ void attn_role(int ab, short* lds_s, const bf* __restrict__ qkvb,
                          float* __restrict__ OP, float* __restrict__ LP){
    int tid = threadIdx.x, lane = tid & 63, wv = tid >> 6;
    int m16 = lane & 15, quad = lane >> 4;
    int rt = ab % 96, cs = (ab / 96) & 3, sg = ab / 384;
    const bf* Qb = qkvb + (size_t)(sg * 3) * NF;
    const bf* Kb = Qb + NF;
    const bf* Vb = Kb + NF;

    int rowbase = rt * 64 + wv * 16;
    short8 Qf0 = *(const short8*)(Qb + (size_t)(rowbase + m16) * 64 + quad * 8);
    short8 Qf1 = *(const short8*)(Qb + (size_t)(rowbase + m16) * 64 + 32 + quad * 8);

    float4v Oc[4];
    #pragma unroll
    for (int t = 0; t < 4; ++t) Oc[t] = (float4v){0.f, 0.f, 0.f, 0.f};
    float l = 0.f;

    const uint32_t lds0 = lds_off32(lds_s);

    auto stage = [&](int cb, int b){
        char* kdst = (char*)lds_s + b * 8192 + wv * 2048;
        char* vdst = (char*)lds_s + 16384 + b * 8192 + wv * 2048;
        #pragma unroll
        for (int inst = 0; inst < 2; ++inst){
            int Lb = wv * 2048 + inst * 1024 + lane * 16;   // dest byte in 8KB buf
            int cl = Lb >> 7;
            int gc = (cl & 32) | (((cl >> 2) & 3) << 3) | (((cl >> 4) & 1) << 2) | (cl & 3);
            int d2 = (Lb & 127) ^ ((cl & 7) << 4);
            const char* ksrc = (const char*)Kb + (((size_t)(cb + gc)) << 7) + d2;
            __builtin_amdgcn_global_load_lds(GLB1(ksrc), LDS3(kdst + inst * 1024), 16, 0, 0);
            int idx = Lb >> 1;
            int vc  = ((idx >> 8) << 2) | ((idx >> 4) & 3);
            int vd  = (((idx >> 6) & 3) << 4) | (idx & 8);
            const char* vsrc = (const char*)Vb + (((size_t)(cb + vc)) << 7) + (vd << 1);
            __builtin_amdgcn_global_load_lds(GLB1(vsrc), LDS3(vdst + inst * 1024), 16, 0, 0);
        }
    };

    const int sw16 = (m16 & 7) << 4;                 // K read swizzle (lane-const)
    const uint32_t kx0 = (uint32_t)(m16 * 128 + ((quad * 16) ^ sw16));
    const uint32_t kx1 = (uint32_t)(m16 * 128 + (((64 + quad * 16)) ^ sw16));
    const uint32_t vx  = (uint32_t)(quad * 1024 + m16 * 2);

    int c0 = cs * (N / 4), c1 = c0 + N / 4;
    stage(c0, 0);
    asm volatile("s_waitcnt vmcnt(0)" ::: "memory");
    __syncthreads();

    int buf = 0;
    for (int cb = c0; cb < c1; cb += 64){
        if (cb + 64 < c1) stage(cb + 64, buf ^ 1);   // prefetch next tile (other buf)
        uint32_t kb0 = lds0 + (uint32_t)(buf * 8192) + kx0;
        uint32_t kb1 = lds0 + (uint32_t)(buf * 8192) + kx1;
        uint32_t vab = lds0 + 16384u + (uint32_t)(buf * 8192) + vx;
        #pragma unroll
        for (int kg = 0; kg < 2; ++kg){
            short8 A[2][2];
            #pragma unroll
            for (int ct = 0; ct < 2; ++ct){
                A[ct][0] = ds_read_b128_off(kb0, kg * 4096 + ct * 2048);
                A[ct][1] = ds_read_b128_off(kb1, kg * 4096 + ct * 2048);
            }
            unsigned long long tr[8];
            #pragma unroll
            for (int dt = 0; dt < 4; ++dt)
                #pragma unroll
                for (int w = 0; w < 2; ++w)
                    tr[dt * 2 + w] = ds_tr16(vab, kg * 4096 + w * 512 + dt * 128);
            asm volatile("s_waitcnt lgkmcnt(8)" ::: "memory");  // K frags done
            __builtin_amdgcn_sched_barrier(0);
            float4v s0 = __builtin_amdgcn_mfma_f32_16x16x32_bf16(
                             A[0][0], Qf0, (float4v){0.f,0.f,0.f,0.f}, 0, 0, 0);
            s0 = __builtin_amdgcn_mfma_f32_16x16x32_bf16(A[0][1], Qf1, s0, 0, 0, 0);
            float4v s1 = __builtin_amdgcn_mfma_f32_16x16x32_bf16(
                             A[1][0], Qf0, (float4v){0.f,0.f,0.f,0.f}, 0, 0, 0);
            s1 = __builtin_amdgcn_mfma_f32_16x16x32_bf16(A[1][1], Qf1, s1, 0, 0, 0);
            float p0[4], p1[4];
            #pragma unroll
            for (int r = 0; r < 4; ++r){
                p0[r] = __builtin_amdgcn_exp2f(s0[r] + L2E);
                p1[r] = __builtin_amdgcn_exp2f(s1[r] + L2E);
                l += p0[r] + p1[r];
            }
            union { unsigned u[4]; short8 s8; } pf;
            pf.u[0] = cvt_pk_bf16(p0[0], p0[1]);
            pf.u[1] = cvt_pk_bf16(p0[2], p0[3]);
            pf.u[2] = cvt_pk_bf16(p1[0], p1[1]);
            pf.u[3] = cvt_pk_bf16(p1[2], p1[3]);
            asm volatile("s_waitcnt lgkmcnt(0)" ::: "memory");  // tr reads done
            __builtin_amdgcn_sched_barrier(0);
            #pragma unroll
            for (int dt = 0; dt < 4; ++dt){
                union { unsigned long long u[2]; short8 s8; } va;
                va.u[0] = tr[dt * 2];
                va.u[1] = tr[dt * 2 + 1];
                Oc[dt] = __builtin_amdgcn_mfma_f32_16x16x32_bf16(va.s8, pf.s8, Oc[dt], 0, 0, 0);
            }
        }
        asm volatile("s_waitcnt vmcnt(0)" ::: "memory");  // prefetch landed
        __syncthreads();                                   // all waves done with buf
        buf ^= 1;
    }

    l += __shfl_xor(l, 16, 64);
    l += __shfl_xor(l, 32, 64);
    int slab = cs * 2 + sg;
    if (quad == 0) LP[(size_t)slab * N + rowbase + m16] = l;
    float* Op = OP + ((size_t)slab * N + rowbase + m16) * 64;
    #pragma unroll
    for (int dt = 0; dt < 4; ++dt)
        *(float4v*)(Op + dt * 16 + quad * 4) = Oc[dt];
}

// Round 10: fill payload stores are NON-TEMPORAL (nt, no-allocate) — the
// scatter previously produced ~61 MB HBM writes (~16x amplification from
// 4B stores dirtying 64B lines across non-coherent XCD L2s). Pay is only
// re-read sequentially by mega, so losing L2 residency costs nothing.
__global__ void __launch_bounds__(256, 3)
attn_fill_kernel(const int* __restrict__ eip, const int* __restrict__ ein,
                 uint32_t* __restrict__ iws, const bf* __restrict__ qkvb,
                 float* __restrict__ OP, float* __restrict__ LP){
    __shared__ __align__(16) short lds_s[16384];   // 32 KiB (attn role only)
    int b = blockIdx.x;
    if (b < 768){
        attn_role(b, lds_s, qkvb, OP, LP);
        return;
    }
    int e = (b - 768) * 256 + threadIdx.x;
    if (e >= Eg) return;
    uint32_t* Cu  = iws + OI_CUR;
    uint32_t* Pay = iws + OI_PAY;
    int rp = clampi(eip[e]), cp = clampi(eip[Eg + e]);
    int rn = clampi(ein[e]), cn = clampi(ein[Eg + e]);
    uint32_t p;
    p = atomicAdd(&Cu[0 * N + rp], 1u);
    if (p < Eg) __builtin_nontemporal_store((uint32_t)e | ((uint32_t)cp << 18), &Pay[0 * (size_t)Eg + p]);
    p = atomicAdd(&Cu[1 * N + cp], 1u);
    if (p < Eg) __builtin_nontemporal_store((uint32_t)e | ((uint32_t)rp << 18), &Pay[1 * (size_t)Eg + p]);
    p = atomicAdd(&Cu[2 * N + rn], 1u);
    if (p < Eg) __builtin_nontemporal_store((uint32_t)e | ((uint32_t)cn << 18), &Pay[2 * (size_t)Eg + p]);
    p = atomicAdd(&Cu[3 * N + cn], 1u);
    if (p < Eg) __builtin_nontemporal_store((uint32_t)e | ((uint32_t)rn << 18), &Pay[3 * (size_t)Eg + p]);
}

// final: 4 rows/wave in registers, readlane broadcast, W streamed once/wave.
// O/l assembled from 4 attn partials + corr buffer (no atomics upstream).
__global__ void final_kernel(const uint32_t* __restrict__ flags,
                             const float* __restrict__ ws, void* __restrict__ outv){
    uint32_t fA = flags[0];
    int t = threadIdx.x, lane = t & 63, wv = t >> 6;
    int row0 = blockIdx.x * 16 + wv * 4;
    float fr[6][4];
    #pragma unroll
    for (int s = 0; s < 2; ++s){
        float onr[4];
        #pragma unroll
        for (int r = 0; r < 4; ++r){
            int i = row0 + r;
            float osum = ws[OF_CO + ((size_t)s * N + i) * 64 + lane];
            float lsum = ws[OF_CL + (size_t)s * N + i];
            #pragma unroll
            for (int cs = 0; cs < 4; ++cs){
                int slab = cs * 2 + s;
                osum += ws[OF_OP + ((size_t)slab * N + i) * 64 + lane];
                lsum += ws[OF_LP + (size_t)slab * N + i];
            }
            onr[r] = sane(osum / fmaxf(lsum, 1e-20f));
        }
        const float* Wo = ws + OF_WO + (size_t)s * 4096;
        float b0 = ws[OF_BO + s * 64 + lane];
        float a[4] = {b0, b0, b0, b0};
        #pragma unroll 16
        for (int d = 0; d < 64; ++d){
            float w = Wo[d * 64 + lane];
            a[0] += rl(onr[0], d) * w;
            a[1] += rl(onr[1], d) * w;
            a[2] += rl(onr[2], d) * w;
            a[3] += rl(onr[3], d) * w;
        }
        #pragma unroll
        for (int r = 0; r < 4; ++r){
            int i = row0 + r;
            float mean = ws[OF_MEAN + (size_t)s * NF + (size_t)i * 64 + lane];
            fr[s][r] = sane(mean + a[r]);
        }
    }
    {
        int g0 = lane >> 5, f = lane & 31;
        #pragma unroll
        for (int r = 0; r < 4; ++r){
            int i = row0 + r;
            fr[2][r] = ws[OF_XF + (size_t)i * 64 + lane];
            fr[3][r] = ws[OF_XF + NF + (size_t)i * 64 + lane];
            fr[4][r] = ws[OF_POOL + ((size_t)g0 * N + i) * 32 + f];
            fr[5][r] = ws[OF_POOL + ((size_t)(2 + g0) * N + i) * 32 + f];
        }
    }
    const float* WF = ws + OF_WF;
    float bf0 = ws[OF_BF + lane];
    float acc[4] = {bf0, bf0, bf0, bf0};
    #pragma unroll
    for (int j = 0; j < 6; ++j){
        #pragma unroll 16
        for (int dd = 0; dd < 64; ++dd){
            float w = WF[(size_t)(j * 64 + dd) * 64 + lane];
            acc[0] += rl(fr[j][0], dd) * w;
            acc[1] += rl(fr[j][1], dd) * w;
            acc[2] += rl(fr[j][2], dd) * w;
            acc[3] += rl(fr[j][3], dd) * w;
        }
    }
    #pragma unroll
    for (int r = 0; r < 4; ++r){
        float a = sane(acc[r]);
        float ss = a * a;
        ss += __shfl_xor(ss, 32, 64); ss += __shfl_xor(ss, 16, 64); ss += __shfl_xor(ss, 8, 64);
        ss += __shfl_xor(ss, 4, 64);  ss += __shfl_xor(ss, 2, 64);  ss += __shfl_xor(ss, 1, 64);
        float out = a / fmaxf(sqrtf(ss), 1e-12f);
        int i = row0 + r;
        if (fA) ((float*)outv)[(size_t)i * 64 + lane] = out;
        else    ((bf*)outv)[(size_t)i * 64 + lane] = __float2bfloat16(out);
    }
}

extern "C" void kernel_launch(void* const* d_in, const int* in_sizes, int n_in,
                              void* d_out, int out_size, void* d_ws, size_t ws_size,
                              hipStream_t stream){
    const int* eip = (const int*)d_in[2];
    const int* ein = (const int*)d_in[3];

    float* ws = (float*)d_ws;
    uint32_t* iws = (uint32_t*)(ws + F_TOTAL);
    uint32_t* flags = iws + OI_FLAG;
    bf* qkvb = (bf*)(ws + OF_QKVB);

    int nu = 4 * N;                        // CSR counts
    zero_sniff_kernel<<<dim3((nu + 255) / 256), 256, 0, stream>>>(
        iws + OI_CNT, nu, d_in[0], d_in[4], d_in[6], d_in[8], flags);
    convert_kernel<<<dim3(3072, 4), 256, 0, stream>>>(
        d_in[0], d_in[1],
        d_in[8],  d_in[10], d_in[12], d_in[16], d_in[18], d_in[20],
        d_in[9],  d_in[11], d_in[13], d_in[17], d_in[19], d_in[21],
        d_in[14], d_in[15], d_in[22], d_in[23],
        d_in[6],  d_in[7],
        eip, ein, iws,
        flags, ws);
    scan_qkv_kernel<<<dim3(4 + 2304), 256, 0, stream>>>(iws, ws, ws);
    attn_fill_kernel<<<dim3(768 + 768), 256, 0, stream>>>(
        eip, ein, iws, qkvb, ws + OF_OP, ws + OF_LP);
    mega_kernel<<<dim3(12288), 256, 0, stream>>>(d_in[4], d_in[5], iws, flags, ws);
    final_kernel<<<dim3(N / 16), 256, 0, stream>>>(flags, ws, d_out);
}

// Round 12
// 185.538 us; speedup vs baseline: 1.0358x; 1.0129x over previous
//
#include <hip/hip_runtime.h>
#include <hip/hip_bf16.h>
#include <stdint.h>

typedef __hip_bfloat16 bf;
typedef __attribute__((ext_vector_type(8))) short short8;
typedef __attribute__((ext_vector_type(4))) short short4v;
typedef __attribute__((ext_vector_type(4))) float float4v;
__device__ __forceinline__ float b2f(bf x){ return __bfloat162float(x); }
__device__ __forceinline__ float bs2f(short s){
    return __uint_as_float(((uint32_t)(uint16_t)s) << 16);
}
__device__ __forceinline__ float sane(float x){ return fminf(fmaxf(x, -1e6f), 1e6f); }
__device__ __forceinline__ float rl(float v, int l){
    return __int_as_float(__builtin_amdgcn_readlane(__float_as_int(v), l));
}

// Problem constants
constexpr int N   = 6144;          // NOT a power of two (3*2^11)!
constexpr int D   = 64;
constexpr int FE  = 32;
constexpr int Eg  = 196608;        // < 2^18 -> edge id packs in 18 bits
constexpr size_t NF = (size_t)N * D;

constexpr float L2E = 1.4426950408889634f;   // log2(e)

__device__ __forceinline__ int clampi(int v){ return v < 0 ? 0 : (v >= N ? N - 1 : v); }
__device__ __forceinline__ float ldf(const void* p, size_t i, uint32_t isf32){
    return isf32 ? ((const float*)p)[i] : b2f(((const bf*)p)[i]);
}

// ---- float workspace layout (floats) ----  ~30.4 MB
constexpr size_t OF_OP   = 0;                           // [4][2][N][D] attn partial O
constexpr size_t OF_LP   = OF_OP + 8*NF;                // [4][2][N]    attn partial L
constexpr size_t OF_CO   = OF_LP + 8*(size_t)N;         // [2][N][D]    corr O (negative)
constexpr size_t OF_CL   = OF_CO + 2*NF;                // [2][N]       corr L (negative)
constexpr size_t OF_MEAN = OF_CL + 2*(size_t)N;         // [2][N][D]
constexpr size_t OF_POOL = OF_MEAN + 2*NF;              // [4][N][FE]
constexpr size_t OF_QKVB = OF_POOL + (size_t)4*N*FE;    // bf16 [2][3][N][D] (Q pre-scaled)
constexpr size_t OF_XF   = OF_QKVB + 3*NF;              // [2][N][D] f32 staged x1,x2
constexpr size_t OF_WA   = OF_XF + 2*NF;                // [6][64][64] attn proj W (f32)
constexpr size_t OF_BA   = OF_WA + 24576;               // [6][64]
constexpr size_t OF_WO   = OF_BA + 384;                 // [2][64][64] Wo_p, Wo_n
constexpr size_t OF_BO   = OF_WO + 8192;                // [2][64]
constexpr size_t OF_WF   = OF_BO + 128;                 // [384][64] final weight
constexpr size_t OF_BF   = OF_WF + 24576;               // [64]
constexpr size_t F_TOTAL = OF_BF + 64;
// ---- u32 workspace (words, after float region) ----  ~3.44 MB
constexpr size_t OI_CNT  = 0;                           // [4][N]
constexpr size_t OI_PTR  = OI_CNT + 4*(size_t)N;        // [4][N+1]
constexpr size_t OI_CUR  = OI_PTR + 4*(size_t)(N+1);    // [4][N]
constexpr size_t OI_PAY  = OI_CUR + 4*(size_t)N;        // [4][Eg]  payload: e | (other<<18)
constexpr size_t OI_FLAG = OI_PAY + 4*(size_t)Eg;       // [4] dtype flags

// zero CSR counts + dtype-sniff fused (last 4 blocks sniff one tensor each).
__global__ void zero_sniff_kernel(uint32_t* __restrict__ uz, int nu,
                                  const void* xA, const void* xB,
                                  const void* xC, const void* xD,
                                  uint32_t* __restrict__ flags){
    int i = blockIdx.x * 256 + threadIdx.x;
    if (i < nu) uz[i] = 0u;
    int sb = (int)gridDim.x - 4;
    if (blockIdx.x >= sb){
        int k = blockIdx.x - sb;
        const void* ps[4] = {xA, xB, xC, xD};
        const bf* p = (const bf*)ps[k];
        __shared__ float red[256];
        int t = threadIdx.x;
        float m = 0.f;
        for (int j = t; j < 1024; j += 256){
            float v = fabsf(b2f(p[j]));
            if (!(v <= 1e9f)) v = 1e9f;
            m = fmaxf(m, v);
        }
        red[t] = m; __syncthreads();
        for (int off = 128; off; off >>= 1){
            if (t < off) red[t] = fmaxf(red[t], red[t + off]);
            __syncthreads();
        }
        if (t == 0) flags[k] = (red[0] > 100.f) ? 1u : 0u;
    }
}

// convert float tensors to f32 staging + CSR count fused (y==3)
__global__ void convert_kernel(const void* x1, const void* x2,
                               const void* W0, const void* W1, const void* W2,
                               const void* W3, const void* W4, const void* W5,
                               const void* B0, const void* B1, const void* B2,
                               const void* B3, const void* B4, const void* B5,
                               const void* Wop, const void* bop,
                               const void* Won, const void* bon,
                               const void* wgt, const void* bia,
                               const int* __restrict__ eip, const int* __restrict__ ein,
                               uint32_t* __restrict__ iws,
                               const uint32_t* __restrict__ flags, float* __restrict__ ws){
    int y = blockIdx.y;
    size_t idx = (size_t)blockIdx.x * 256 + threadIdx.x;
    if (y == 0){
        uint32_t fA = flags[0];
        float v = (idx < NF) ? ldf(x1, idx, fA) : ldf(x2, idx - NF, fA);
        ws[OF_XF + idx] = sane(v);
    } else if (y == 1){
        if (idx >= 33280) return;
        uint32_t fD = flags[3];
        float v;
        if (idx < 24576){
            int m = (int)(idx >> 12), sub = (int)(idx & 4095);
            const void* W = (m==0)?W0:(m==1)?W1:(m==2)?W2:(m==3)?W3:(m==4)?W4:W5;
            v = ldf(W, sub, fD);
        } else if (idx < 24960){
            int m = (int)((idx - 24576) >> 6), sub = (int)(idx & 63);
            const void* B = (m==0)?B0:(m==1)?B1:(m==2)?B2:(m==3)?B3:(m==4)?B4:B5;
            v = ldf(B, sub, fD);
        } else if (idx < 33152){
            int k = (int)((idx - 24960) >> 12), sub = (int)(idx & 4095);
            v = ldf(k ? Won : Wop, sub, fD);
        } else {
            int k = (int)((idx - 33152) >> 6), sub = (int)(idx & 63);
            v = ldf(k ? bon : bop, sub, fD);
        }
        ws[OF_WA + idx] = sane(v);
    } else if (y == 2){
        if (idx >= 24640) return;
        uint32_t fC = flags[2];
        float v = (idx < 24576) ? ldf(wgt, idx, fC) : ldf(bia, idx - 24576, fC);
        ws[OF_WF + idx] = sane(v);
    } else {
        // CSR count (only first 768 x-blocks carry edges)
        if (idx >= (size_t)Eg) return;
        int e = (int)idx;
        uint32_t* cnt = iws + OI_CNT;
        atomicAdd(&cnt[0 * N + clampi(eip[e])],      1u);
        atomicAdd(&cnt[1 * N + clampi(eip[Eg + e])], 1u);
        atomicAdd(&cnt[2 * N + clampi(ein[e])],      1u);
        atomicAdd(&cnt[3 * N + clampi(ein[Eg + e])], 1u);
    }
}

// ---- scan + qkv fused: blocks 0..3 = CSR exclusive scan; rest = qkv ----
__device__ __forceinline__ void scan_role(int b, uint32_t* __restrict__ iws){
    int t = threadIdx.x;
    const uint32_t* c = iws + OI_CNT + (size_t)b * N;
    uint32_t* P  = iws + OI_PTR + (size_t)b * (N + 1);
    uint32_t* Cu = iws + OI_CUR + (size_t)b * N;
    constexpr int K = N / 256;
    int base = t * K;
    uint32_t s = 0;
    for (int k = 0; k < K; ++k) s += c[base + k];
    __shared__ uint32_t sums[256];
    sums[t] = s; __syncthreads();
    for (int off = 1; off < 256; off <<= 1){
        uint32_t v = (t >= off) ? sums[t - off] : 0u;
        __syncthreads();
        sums[t] += v;
        __syncthreads();
    }
    uint32_t run = (t == 0) ? 0u : sums[t - 1];
    for (int k = 0; k < K; ++k){ P[base + k] = run; Cu[base + k] = run; run += c[base + k]; }
    if (t == 255) P[N] = run;
}

__device__ __forceinline__ void qkv_role(int q, const float* __restrict__ ws_ro,
                                         float* __restrict__ ws){
    int m = q / 384, xb = q - m * 384;
    int t = threadIdx.x, lane = t & 63, wv = t >> 6;
    int row0 = xb * 16 + wv * 4;
    const float* x = ws_ro + OF_XF + (m < 3 ? 0 : NF) + (size_t)row0 * 64;
    const float* W = ws_ro + OF_WA + (size_t)m * 4096;
    float x0 = x[lane], x1 = x[64 + lane], x2 = x[128 + lane], x3 = x[192 + lane];
    float bbias = ws_ro[OF_BA + m * 64 + lane];
    float a0 = bbias, a1 = bbias, a2 = bbias, a3 = bbias;
    #pragma unroll 16
    for (int d = 0; d < 64; ++d){
        float w = W[d * 64 + lane];
        a0 += rl(x0, d) * w;
        a1 += rl(x1, d) * w;
        a2 += rl(x2, d) * w;
        a3 += rl(x3, d) * w;
    }
    float sc = (m == 0 || m == 3) ? 0.125f * L2E : 1.f;
    bf* qkvb = (bf*)(ws + OF_QKVB) + (size_t)m * NF + (size_t)row0 * 64;
    qkvb[lane]       = __float2bfloat16(sane(a0) * sc);
    qkvb[64 + lane]  = __float2bfloat16(sane(a1) * sc);
    qkvb[128 + lane] = __float2bfloat16(sane(a2) * sc);
    qkvb[192 + lane] = __float2bfloat16(sane(a3) * sc);
}

__global__ void scan_qkv_kernel(uint32_t* __restrict__ iws,
                                const float* __restrict__ ws_ro, float* __restrict__ ws){
    int b = blockIdx.x;
    if (b < 4) scan_role(b, iws);
    else       qkv_role(b - 4, ws_ro, ws);
}

// ---- mega kernel roles (R7 config: 2-edge unrolled gathers) ----

// mean: 4 groups x 16 lanes; lane covers d = t*4..t*4+3 (float4 gathers)
__device__ __forceinline__ void mean_role(int b, const uint32_t* __restrict__ iws,
                                          const float* __restrict__ ws_ro, float* __restrict__ ws){
    int wid = threadIdx.x >> 6, lane = threadIdx.x & 63;
    int gw = b * 4 + wid;
    int sign = gw >= N;
    int i = gw - sign * N;
    int h = lane >> 4, t = lane & 15;
    const float* x = ws_ro + OF_XF + (size_t)sign * NF;
    int csr = sign ? 2 : 0;
    const uint32_t* P   = iws + OI_PTR + (size_t)csr * (N + 1);
    const uint32_t* Pay = iws + OI_PAY + (size_t)csr * Eg;
    uint32_t p0 = P[i], p1 = P[i + 1];
    if (p1 > (uint32_t)Eg) p1 = Eg;
    if (p0 > p1) p0 = p1;
    float4v acc = (float4v){0.f, 0.f, 0.f, 0.f};
    if (h == 0) acc = *(const float4v*)(x + (size_t)i * 64 + t * 4);   // self loop
    uint32_t p = p0 + h;
    for (; p + 4 < p1; p += 8){
        int cA = (int)(Pay[p] >> 18);
        int cB = (int)(Pay[p + 4] >> 18);
        float4v vA = *(const float4v*)(x + (size_t)cA * 64 + t * 4);
        float4v vB = *(const float4v*)(x + (size_t)cB * 64 + t * 4);
        acc[0] += vA[0] + vB[0]; acc[1] += vA[1] + vB[1];
        acc[2] += vA[2] + vB[2]; acc[3] += vA[3] + vB[3];
    }
    if (p < p1){
        int c = (int)(Pay[p] >> 18);
        float4v v = *(const float4v*)(x + (size_t)c * 64 + t * 4);
        acc[0] += v[0]; acc[1] += v[1]; acc[2] += v[2]; acc[3] += v[3];
    }
    #pragma unroll
    for (int j = 0; j < 4; ++j){
        acc[j] += __shfl_xor(acc[j], 16, 64);
        acc[j] += __shfl_xor(acc[j], 32, 64);
    }
    if (h == 0){
        float invc = 1.f / (float)(p1 - p0 + 1);
        float* dst = ws + OF_MEAN + (size_t)sign * NF + (size_t)i * 64 + t * 4;
        #pragma unroll
        for (int j = 0; j < 4; ++j) dst[j] = sane(acc[j] * invc);
    }
}

// pool: 8 groups x 8 lanes; lane covers f = t*4..t*4+3; 16 edges in flight
__device__ __forceinline__ void pool_role(int b, const void* __restrict__ efp,
                                          const void* __restrict__ efn,
                                          const uint32_t* __restrict__ iws,
                                          uint32_t fB, float* __restrict__ ws){
    int wid = threadIdx.x >> 6, lane = threadIdx.x & 63;
    int gw = b * 4 + wid;
    int g = gw / N, i = gw - g * N;
    const void* ef = (g < 2) ? efp : efn;
    const uint32_t* P   = iws + OI_PTR + (size_t)g * (N + 1);
    const uint32_t* Pay = iws + OI_PAY + (size_t)g * Eg;
    int h = lane >> 3, t = lane & 7;
    uint32_t p0 = P[i], p1 = P[i + 1];
    if (p1 > (uint32_t)Eg) p1 = Eg;
    if (p0 > p1) p0 = p1;
    float m0 = 0.f, m1 = 0.f, m2 = 0.f, m3 = 0.f;
    uint32_t p = p0 + h;
    if (fB){
        const float* E = (const float*)ef;
        for (; p + 8 < p1; p += 16){
            uint32_t eA = Pay[p] & 0x3FFFFu, eB = Pay[p + 8] & 0x3FFFFu;
            float4v vA = *(const float4v*)(E + (size_t)eA * 32 + t * 4);
            float4v vB = *(const float4v*)(E + (size_t)eB * 32 + t * 4);
            m0 = fmaxf(m0, fmaxf(vA[0], vB[0])); m1 = fmaxf(m1, fmaxf(vA[1], vB[1]));
            m2 = fmaxf(m2, fmaxf(vA[2], vB[2])); m3 = fmaxf(m3, fmaxf(vA[3], vB[3]));
        }
        if (p < p1){
            uint32_t e = Pay[p] & 0x3FFFFu;
            float4v v = *(const float4v*)(E + (size_t)e * 32 + t * 4);
            m0 = fmaxf(m0, v[0]); m1 = fmaxf(m1, v[1]);
            m2 = fmaxf(m2, v[2]); m3 = fmaxf(m3, v[3]);
        }
    } else {
        const short* E = (const short*)ef;
        for (; p + 8 < p1; p += 16){
            uint32_t eA = Pay[p] & 0x3FFFFu, eB = Pay[p + 8] & 0x3FFFFu;
            short4v vA = *(const short4v*)(E + (size_t)eA * 32 + t * 4);
            short4v vB = *(const short4v*)(E + (size_t)eB * 32 + t * 4);
            m0 = fmaxf(m0, fmaxf(bs2f(vA[0]), bs2f(vB[0])));
            m1 = fmaxf(m1, fmaxf(bs2f(vA[1]), bs2f(vB[1])));
            m2 = fmaxf(m2, fmaxf(bs2f(vA[2]), bs2f(vB[2])));
            m3 = fmaxf(m3, fmaxf(bs2f(vA[3]), bs2f(vB[3])));
        }
        if (p < p1){
            uint32_t e = Pay[p] & 0x3FFFFu;
            short4v v = *(const short4v*)(E + (size_t)e * 32 + t * 4);
            m0 = fmaxf(m0, bs2f(v[0])); m1 = fmaxf(m1, bs2f(v[1]));
            m2 = fmaxf(m2, bs2f(v[2])); m3 = fmaxf(m3, bs2f(v[3]));
        }
    }
    #pragma unroll
    for (int mk = 8; mk <= 32; mk <<= 1){
        m0 = fmaxf(m0, __shfl_xor(m0, mk, 64));
        m1 = fmaxf(m1, __shfl_xor(m1, mk, 64));
        m2 = fmaxf(m2, __shfl_xor(m2, mk, 64));
        m3 = fmaxf(m3, __shfl_xor(m3, mk, 64));
    }
    m0 = sane(m0); m1 = sane(m1); m2 = sane(m2); m3 = sane(m3);
    float ss = m0 * m0 + m1 * m1 + m2 * m2 + m3 * m3;
    ss += __shfl_xor(ss, 1, 64); ss += __shfl_xor(ss, 2, 64); ss += __shfl_xor(ss, 4, 64);
    float inv = 1.f / fmaxf(sqrtf(ss), 1e-12f);
    if (h == 0){
        float* dst = ws + OF_POOL + ((size_t)g * N + i) * 32 + t * 4;
        dst[0] = sane(m0 * inv); dst[1] = sane(m1 * inv);
        dst[2] = sane(m2 * inv); dst[3] = sane(m3 * inv);
    }
}

// corr: 8 groups x 8 lanes; 2-edge unroll; diagonal = slot p1.
// Plain stores into CO/CL (negated), no atomics.
__device__ __forceinline__ void corr_role(int b, const uint32_t* __restrict__ iws,
                                          const float* __restrict__ ws_ro,
                                          float* __restrict__ CO, float* __restrict__ CL){
    int wid = threadIdx.x >> 6, lane = threadIdx.x & 63;
    int gw = b * 4 + wid;
    int sg = gw >= N;
    int i = gw - sg * N;
    int h = lane >> 3, t = lane & 7;
    const bf* Qb = (const bf*)(ws_ro + OF_QKVB) + (size_t)(sg * 3) * NF;
    const short* Kb = (const short*)(Qb + NF);
    const short* Vb = Kb + NF;
    const int csr = sg ? 2 : 0;
    const uint32_t* Pp  = iws + OI_PTR + (size_t)csr * (N + 1);
    const uint32_t* Pay = iws + OI_PAY + (size_t)csr * Eg;
    uint32_t p0 = Pp[i], p1 = Pp[i + 1];
    if (p1 > (uint32_t)Eg) p1 = Eg;
    if (p0 > p1) p0 = p1;
    float qf[8];
    {
        short8 qv = *(const short8*)((const short*)Qb + (size_t)i * 64 + t * 8);
        #pragma unroll
        for (int j = 0; j < 8; ++j) qf[j] = bs2f(qv[j]);   // pre-scaled 0.125*log2e
    }
    float accO[8] = {0.f,0.f,0.f,0.f,0.f,0.f,0.f,0.f};
    float accL = 0.f;
    constexpr float C = 0.63212055882f;      // 1 - 1/e
    uint32_t p = p0 + h;
    for (; p + 8 <= p1; p += 16){
        int cA = (int)(Pay[p] >> 18);
        int cB = (p + 8 < p1) ? (int)(Pay[p + 8] >> 18) : i;
        short8 kvA = *(const short8*)(Kb + (size_t)cA * 64 + t * 8);
        short8 kvB = *(const short8*)(Kb + (size_t)cB * 64 + t * 8);
        short8 vvA = *(const short8*)(Vb + (size_t)cA * 64 + t * 8);
        short8 vvB = *(const short8*)(Vb + (size_t)cB * 64 + t * 8);
        float sA = qf[0] * bs2f(kvA[0]);
        float sB = qf[0] * bs2f(kvB[0]);
        #pragma unroll
        for (int j = 1; j < 8; ++j){ sA += qf[j] * bs2f(kvA[j]); sB += qf[j] * bs2f(kvB[j]); }
        sA += __shfl_xor(sA, 1, 64); sB += __shfl_xor(sB, 1, 64);
        sA += __shfl_xor(sA, 2, 64); sB += __shfl_xor(sB, 2, 64);
        sA += __shfl_xor(sA, 4, 64); sB += __shfl_xor(sB, 4, 64);
        float fA = C * __builtin_amdgcn_exp2f(sA + L2E);
        float fB = C * __builtin_amdgcn_exp2f(sB + L2E);
        accL += fA + fB;
        #pragma unroll
        for (int j = 0; j < 8; ++j) accO[j] += fA * bs2f(vvA[j]) + fB * bs2f(vvB[j]);
    }
    if (p <= p1){
        int c = (p < p1) ? (int)(Pay[p] >> 18) : i;
        short8 kv = *(const short8*)(Kb + (size_t)c * 64 + t * 8);
        short8 vv = *(const short8*)(Vb + (size_t)c * 64 + t * 8);
        float s = qf[0] * bs2f(kv[0]);
        #pragma unroll
        for (int j = 1; j < 8; ++j) s += qf[j] * bs2f(kv[j]);
        s += __shfl_xor(s, 1, 64);
        s += __shfl_xor(s, 2, 64);
        s += __shfl_xor(s, 4, 64);
        float f = C * __builtin_amdgcn_exp2f(s + L2E);
        accL += f;
        #pragma unroll
        for (int j = 0; j < 8; ++j) accO[j] += f * bs2f(vv[j]);
    }
    #pragma unroll
    for (int j = 0; j < 8; ++j){
        accO[j] += __shfl_xor(accO[j], 8, 64);
        accO[j] += __shfl_xor(accO[j], 16, 64);
        accO[j] += __shfl_xor(accO[j], 32, 64);
    }
    accL += __shfl_xor(accL, 8, 64);
    accL += __shfl_xor(accL, 16, 64);
    accL += __shfl_xor(accL, 32, 64);
    if (h == 0){
        float* Op = CO + ((size_t)sg * N + i) * 64 + t * 8;
        #pragma unroll
        for (int j = 0; j < 8; ++j) Op[j] = -accO[j];
        if (t == 0) CL[(size_t)sg * N + i] = -accL;
    }
}

__global__ void mega_kernel(const void* __restrict__ efp, const void* __restrict__ efn,
                            const uint32_t* __restrict__ iws,
                            const uint32_t* __restrict__ flags, float* __restrict__ ws){
    int b = blockIdx.x;
    if (b < 3072)       mean_role(b, iws, ws, ws);
    else if (b < 9216)  pool_role(b - 3072, efp, efn, iws, flags[1], ws);
    else                corr_role(b - 9216, iws, ws, ws + OF_CO, ws + OF_CL);
}

// ---- dense attention role + CSR fill role fused ----
#define GLB1(p) ((const __attribute__((address_space(1))) void*)(p))
#define LDS3(p) ((__attribute__((address_space(3))) void*)(p))

__device__ __forceinline__ uint32_t lds_off32(const void* p){
    return (uint32_t)(uintptr_t)(__attribute__((address_space(3))) const void*)p;
}
__device__ __forceinline__ short8 ds_read_b128_off(uint32_t addr, int off){
    short8 r;
    asm volatile("ds_read_b128 %0, %1 offset:%2" : "=v"(r) : "v"(addr), "i"(off));
    return r;
}
__device__ __forceinline__ unsigned long long ds_tr16(uint32_t addr, int off){
    unsigned long long r;
    asm volatile("ds_read_b64_tr_b16 %0, %1 offset:%2" : "=v"(r) : "v"(addr), "i"(off));
    return r;
}
__device__ __forceinline__ unsigned cvt_pk_bf16(float lo, float hi){
    unsigned r;
    asm("v_cvt_pk_bf16_f32 %0, %1, %2" : "=v"(r) : "v"(lo), "v"(hi));
    return r;
}

__device__ void attn_role(int ab, short* lds_s, const bf* __restrict__ qkvb,
                          float* __restrict__ OP, float* __restrict__ LP){
    int tid = threadIdx.x, lane = tid & 63, wv = tid >> 6;
    int m16 = lane & 15, quad = lane >> 4;
    int rt = ab % 96, cs = (ab / 96) & 3, sg = ab / 384;
    const bf* Qb = qkvb + (size_t)(sg * 3) * NF;
    const bf* Kb = Qb + NF;
    const bf* Vb = Kb + NF;

    int rowbase = rt * 64 + wv * 16;
    short8 Qf0 = *(const short8*)(Qb + (size_t)(rowbase + m16) * 64 + quad * 8);
    short8 Qf1 = *(const short8*)(Qb + (size_t)(rowbase + m16) * 64 + 32 + quad * 8);

    float4v Oc[4];
    #pragma unroll
    for (int t = 0; t < 4; ++t) Oc[t] = (float4v){0.f, 0.f, 0.f, 0.f};
    float l = 0.f;

    const uint32_t lds0 = lds_off32(lds_s);

    auto stage = [&](int cb, int b){
        char* kdst = (char*)lds_s + b * 8192 + wv * 2048;
        char* vdst = (char*)lds_s + 16384 + b * 8192 + wv * 2048;
        #pragma unroll
        for (int inst = 0; inst < 2; ++inst){
            int Lb = wv * 2048 + inst * 1024 + lane * 16;   // dest byte in 8KB buf
            int cl = Lb >> 7;
            int gc = (cl & 32) | (((cl >> 2) & 3) << 3) | (((cl >> 4) & 1) << 2) | (cl & 3);
            int d2 = (Lb & 127) ^ ((cl & 7) << 4);
            const char* ksrc = (const char*)Kb + (((size_t)(cb + gc)) << 7) + d2;
            __builtin_amdgcn_global_load_lds(GLB1(ksrc), LDS3(kdst + inst * 1024), 16, 0, 0);
            int idx = Lb >> 1;
            int vc  = ((idx >> 8) << 2) | ((idx >> 4) & 3);
            int vd  = (((idx >> 6) & 3) << 4) | (idx & 8);
            const char* vsrc = (const char*)Vb + (((size_t)(cb + vc)) << 7) + (vd << 1);
            __builtin_amdgcn_global_load_lds(GLB1(vsrc), LDS3(vdst + inst * 1024), 16, 0, 0);
        }
    };

    const int sw16 = (m16 & 7) << 4;                 // K read swizzle (lane-const)
    const uint32_t kx0 = (uint32_t)(m16 * 128 + ((quad * 16) ^ sw16));
    const uint32_t kx1 = (uint32_t)(m16 * 128 + (((64 + quad * 16)) ^ sw16));
    const uint32_t vx  = (uint32_t)(quad * 1024 + m16 * 2);

    int c0 = cs * (N / 4), c1 = c0 + N / 4;
    stage(c0, 0);
    asm volatile("s_waitcnt vmcnt(0)" ::: "memory");
    __syncthreads();

    int buf = 0;
    for (int cb = c0; cb < c1; cb += 64){
        if (cb + 64 < c1) stage(cb + 64, buf ^ 1);   // prefetch next tile (other buf)
        uint32_t kb0 = lds0 + (uint32_t)(buf * 8192) + kx0;
        uint32_t kb1 = lds0 + (uint32_t)(buf * 8192) + kx1;
        uint32_t vab = lds0 + 16384u + (uint32_t)(buf * 8192) + vx;
        #pragma unroll
        for (int kg = 0; kg < 2; ++kg){
            short8 A[2][2];
            #pragma unroll
            for (int ct = 0; ct < 2; ++ct){
                A[ct][0] = ds_read_b128_off(kb0, kg * 4096 + ct * 2048);
                A[ct][1] = ds_read_b128_off(kb1, kg * 4096 + ct * 2048);
            }
            unsigned long long tr[8];
            #pragma unroll
            for (int dt = 0; dt < 4; ++dt)
                #pragma unroll
                for (int w = 0; w < 2; ++w)
                    tr[dt * 2 + w] = ds_tr16(vab, kg * 4096 + w * 512 + dt * 128);
            asm volatile("s_waitcnt lgkmcnt(8)" ::: "memory");  // K frags done
            __builtin_amdgcn_sched_barrier(0);
            float4v s0 = __builtin_amdgcn_mfma_f32_16x16x32_bf16(
                             A[0][0], Qf0, (float4v){0.f,0.f,0.f,0.f}, 0, 0, 0);
            s0 = __builtin_amdgcn_mfma_f32_16x16x32_bf16(A[0][1], Qf1, s0, 0, 0, 0);
            float4v s1 = __builtin_amdgcn_mfma_f32_16x16x32_bf16(
                             A[1][0], Qf0, (float4v){0.f,0.f,0.f,0.f}, 0, 0, 0);
            s1 = __builtin_amdgcn_mfma_f32_16x16x32_bf16(A[1][1], Qf1, s1, 0, 0, 0);
            float p0[4], p1[4];
            #pragma unroll
            for (int r = 0; r < 4; ++r){
                p0[r] = __builtin_amdgcn_exp2f(s0[r] + L2E);
                p1[r] = __builtin_amdgcn_exp2f(s1[r] + L2E);
                l += p0[r] + p1[r];
            }
            union { unsigned u[4]; short8 s8; } pf;
            pf.u[0] = cvt_pk_bf16(p0[0], p0[1]);
            pf.u[1] = cvt_pk_bf16(p0[2], p0[3]);
            pf.u[2] = cvt_pk_bf16(p1[0], p1[1]);
            pf.u[3] = cvt_pk_bf16(p1[2], p1[3]);
            asm volatile("s_waitcnt lgkmcnt(0)" ::: "memory");  // tr reads done
            __builtin_amdgcn_sched_barrier(0);
            #pragma unroll
            for (int dt = 0; dt < 4; ++dt){
                union { unsigned long long u[2]; short8 s8; } va;
                va.u[0] = tr[dt * 2];
                va.u[1] = tr[dt * 2 + 1];
                Oc[dt] = __builtin_amdgcn_mfma_f32_16x16x32_bf16(va.s8, pf.s8, Oc[dt], 0, 0, 0);
            }
        }
        asm volatile("s_waitcnt vmcnt(0)" ::: "memory");  // prefetch landed
        __syncthreads();                                   // all waves done with buf
        buf ^= 1;
    }

    l += __shfl_xor(l, 16, 64);
    l += __shfl_xor(l, 32, 64);
    int slab = cs * 2 + sg;
    if (quad == 0) LP[(size_t)slab * N + rowbase + m16] = l;
    float* Op = OP + ((size_t)slab * N + rowbase + m16) * 64;
    #pragma unroll
    for (int dt = 0; dt < 4; ++dt)
        *(float4v*)(Op + dt * 16 + quad * 4) = Oc[dt];
}

// Round 11: nt stores reverted — R10 measured WRITE_SIZE 61->67.7 MB and
// +2.5 us (nt bypasses the L2 merging that was helping). Plain stores.
__global__ void __launch_bounds__(256, 3)
attn_fill_kernel(const int* __restrict__ eip, const int* __restrict__ ein,
                 uint32_t* __restrict__ iws, const bf* __restrict__ qkvb,
                 float* __restrict__ OP, float* __restrict__ LP){
    __shared__ __align__(16) short lds_s[16384];   // 32 KiB (attn role only)
    int b = blockIdx.x;
    if (b < 768){
        attn_role(b, lds_s, qkvb, OP, LP);
        return;
    }
    int e = (b - 768) * 256 + threadIdx.x;
    if (e >= Eg) return;
    uint32_t* Cu  = iws + OI_CUR;
    uint32_t* Pay = iws + OI_PAY;
    int rp = clampi(eip[e]), cp = clampi(eip[Eg + e]);
    int rn = clampi(ein[e]), cn = clampi(ein[Eg + e]);
    uint32_t p;
    p = atomicAdd(&Cu[0 * N + rp], 1u); if (p < Eg) Pay[0 * (size_t)Eg + p] = (uint32_t)e | ((uint32_t)cp << 18);
    p = atomicAdd(&Cu[1 * N + cp], 1u); if (p < Eg) Pay[1 * (size_t)Eg + p] = (uint32_t)e | ((uint32_t)rp << 18);
    p = atomicAdd(&Cu[2 * N + rn], 1u); if (p < Eg) Pay[2 * (size_t)Eg + p] = (uint32_t)e | ((uint32_t)cn << 18);
    p = atomicAdd(&Cu[3 * N + cn], 1u); if (p < Eg) Pay[3 * (size_t)Eg + p] = (uint32_t)e | ((uint32_t)rn << 18);
}

// final: 4 rows/wave in registers, readlane broadcast, W streamed once/wave.
// O/l assembled from 4 attn partials + corr buffer (no atomics upstream).
__global__ void final_kernel(const uint32_t* __restrict__ flags,
                             const float* __restrict__ ws, void* __restrict__ outv){
    uint32_t fA = flags[0];
    int t = threadIdx.x, lane = t & 63, wv = t >> 6;
    int row0 = blockIdx.x * 16 + wv * 4;
    float fr[6][4];
    #pragma unroll
    for (int s = 0; s < 2; ++s){
        float onr[4];
        #pragma unroll
        for (int r = 0; r < 4; ++r){
            int i = row0 + r;
            float osum = ws[OF_CO + ((size_t)s * N + i) * 64 + lane];
            float lsum = ws[OF_CL + (size_t)s * N + i];
            #pragma unroll
            for (int cs = 0; cs < 4; ++cs){
                int slab = cs * 2 + s;
                osum += ws[OF_OP + ((size_t)slab * N + i) * 64 + lane];
                lsum += ws[OF_LP + (size_t)slab * N + i];
            }
            onr[r] = sane(osum / fmaxf(lsum, 1e-20f));
        }
        const float* Wo = ws + OF_WO + (size_t)s * 4096;
        float b0 = ws[OF_BO + s * 64 + lane];
        float a[4] = {b0, b0, b0, b0};
        #pragma unroll 16
        for (int d = 0; d < 64; ++d){
            float w = Wo[d * 64 + lane];
            a[0] += rl(onr[0], d) * w;
            a[1] += rl(onr[1], d) * w;
            a[2] += rl(onr[2], d) * w;
            a[3] += rl(onr[3], d) * w;
        }
        #pragma unroll
        for (int r = 0; r < 4; ++r){
            int i = row0 + r;
            float mean = ws[OF_MEAN + (size_t)s * NF + (size_t)i * 64 + lane];
            fr[s][r] = sane(mean + a[r]);
        }
    }
    {
        int g0 = lane >> 5, f = lane & 31;
        #pragma unroll
        for (int r = 0; r < 4; ++r){
            int i = row0 + r;
            fr[2][r] = ws[OF_XF + (size_t)i * 64 + lane];
            fr[3][r] = ws[OF_XF + NF + (size_t)i * 64 + lane];
            fr[4][r] = ws[OF_POOL + ((size_t)g0 * N + i) * 32 + f];
            fr[5][r] = ws[OF_POOL + ((size_t)(2 + g0) * N + i) * 32 + f];
        }
    }
    const float* WF = ws + OF_WF;
    float bf0 = ws[OF_BF + lane];
    float acc[4] = {bf0, bf0, bf0, bf0};
    #pragma unroll
    for (int j = 0; j < 6; ++j){
        #pragma unroll 16
        for (int dd = 0; dd < 64; ++dd){
            float w = WF[(size_t)(j * 64 + dd) * 64 + lane];
            acc[0] += rl(fr[j][0], dd) * w;
            acc[1] += rl(fr[j][1], dd) * w;
            acc[2] += rl(fr[j][2], dd) * w;
            acc[3] += rl(fr[j][3], dd) * w;
        }
    }
    #pragma unroll
    for (int r = 0; r < 4; ++r){
        float a = sane(acc[r]);
        float ss = a * a;
        ss += __shfl_xor(ss, 32, 64); ss += __shfl_xor(ss, 16, 64); ss += __shfl_xor(ss, 8, 64);
        ss += __shfl_xor(ss, 4, 64);  ss += __shfl_xor(ss, 2, 64);  ss += __shfl_xor(ss, 1, 64);
        float out = a / fmaxf(sqrtf(ss), 1e-12f);
        int i = row0 + r;
        if (fA) ((float*)outv)[(size_t)i * 64 + lane] = out;
        else    ((bf*)outv)[(size_t)i * 64 + lane] = __float2bfloat16(out);
    }
}

extern "C" void kernel_launch(void* const* d_in, const int* in_sizes, int n_in,
                              void* d_out, int out_size, void* d_ws, size_t ws_size,
                              hipStream_t stream){
    const int* eip = (const int*)d_in[2];
    const int* ein = (const int*)d_in[3];

    float* ws = (float*)d_ws;
    uint32_t* iws = (uint32_t*)(ws + F_TOTAL);
    uint32_t* flags = iws + OI_FLAG;
    bf* qkvb = (bf*)(ws + OF_QKVB);

    int nu = 4 * N;                        // CSR counts
    zero_sniff_kernel<<<dim3((nu + 255) / 256), 256, 0, stream>>>(
        iws + OI_CNT, nu, d_in[0], d_in[4], d_in[6], d_in[8], flags);
    convert_kernel<<<dim3(3072, 4), 256, 0, stream>>>(
        d_in[0], d_in[1],
        d_in[8],  d_in[10], d_in[12], d_in[16], d_in[18], d_in[20],
        d_in[9],  d_in[11], d_in[13], d_in[17], d_in[19], d_in[21],
        d_in[14], d_in[15], d_in[22], d_in[23],
        d_in[6],  d_in[7],
        eip, ein, iws,
        flags, ws);
    scan_qkv_kernel<<<dim3(4 + 2304), 256, 0, stream>>>(iws, ws, ws);
    attn_fill_kernel<<<dim3(768 + 768), 256, 0, stream>>>(
        eip, ein, iws, qkvb, ws + OF_OP, ws + OF_LP);
    mega_kernel<<<dim3(12288), 256, 0, stream>>>(d_in[4], d_in[5], iws, flags, ws);
    final_kernel<<<dim3(N / 16), 256, 0, stream>>>(flags, ws, d_out);
}